// Round 5
// baseline (724.684 us; speedup 1.0000x reference)
//
#include <hip/hip_runtime.h>
#include <stdint.h>

#define NN 200000
#define NE 800000
#define FIN 128
#define NG 8000
#define EPSV 1e-5f
#define NBS ((NN + 255) / 256)   // 782 scan blocks

// ---- int degree histogram over dst ----
__global__ void k_cnt(const int* __restrict__ dst, int* __restrict__ cnt) {
    int e = blockIdx.x * 256 + threadIdx.x;
    if (e < NE) atomicAdd(&cnt[dst[e]], 1);
}

// ---- per-256-chunk sums ----
__global__ void k_blocksum(const int* __restrict__ cnt, int* __restrict__ bsum) {
    __shared__ int sh[256];
    int b = blockIdx.x, t = threadIdx.x;
    int idx = b * 256 + t;
    sh[t] = (idx < NN) ? cnt[idx] : 0;
    __syncthreads();
    for (int o = 128; o > 0; o >>= 1) {
        if (t < o) sh[t] += sh[t + o];
        __syncthreads();
    }
    if (t == 0) bsum[b] = sh[0];
}

// ---- single-block scan of chunk sums -> exclusive prefixes ----
__global__ __launch_bounds__(1024) void k_scanb(const int* __restrict__ bsum, int* __restrict__ bpre) {
    __shared__ int sh[1024];
    int t = threadIdx.x;
    int v = (t < NBS) ? bsum[t] : 0;
    sh[t] = v;
    __syncthreads();
    for (int o = 1; o < 1024; o <<= 1) {
        int add = (t >= o) ? sh[t - o] : 0;
        __syncthreads();
        sh[t] += add;
        __syncthreads();
    }
    if (t < NBS) bpre[t] = sh[t] - v;  // exclusive
}

// ---- per-chunk scan + offset -> rowstart (exclusive) ----
__global__ void k_scanchunk(const int* __restrict__ cnt, const int* __restrict__ bpre,
                            int* __restrict__ rowstart) {
    __shared__ int sh[256];
    int b = blockIdx.x, t = threadIdx.x;
    int idx = b * 256 + t;
    int v = (idx < NN) ? cnt[idx] : 0;
    sh[t] = v;
    __syncthreads();
    for (int o = 1; o < 256; o <<= 1) {
        int add = (t >= o) ? sh[t - o] : 0;
        __syncthreads();
        sh[t] += add;
        __syncthreads();
    }
    if (idx < NN) rowstart[idx] = bpre[b] + sh[t] - v;
    if (idx == 0) rowstart[NN] = NE;
}

// ---- dis = rsqrt(1+deg), IN PLACE over cnt (int -> float reinterpret) ----
__global__ void k_dis(int* __restrict__ cnt) {
    int n = blockIdx.x * 256 + threadIdx.x;
    if (n < NN) {
        float d = rsqrtf(1.0f + (float)cnt[n]);
        ((float*)cnt)[n] = d;
    }
}

// ---- fill CSR: csr[pos] = src, bucketed by dst ----
__global__ void k_fill(const int* __restrict__ src, const int* __restrict__ dst,
                       int* __restrict__ cursor, int* __restrict__ csr) {
    int e = blockIdx.x * 256 + threadIdx.x;
    if (e < NE) {
        int pos = atomicAdd(&cursor[dst[e]], 1);
        csr[pos] = src[e];
    }
}

// ---- graph start offsets from sorted batch ----
__global__ void k_starts(const int* __restrict__ batch, int* __restrict__ startg) {
    int n = blockIdx.x * 256 + threadIdx.x;
    if (n >= NN) return;
    int b = batch[n];
    int prev = (n == 0) ? -1 : batch[n - 1];
    for (int g = prev + 1; g <= b; ++g) startg[g] = n;
    if (n == NN - 1) {
        for (int g = b + 1; g <= NG; ++g) startg[g] = NN;
    }
}

// ---- fused instance-norm + conv1 (one block per graph):
//      p1 = ((x - mean)*istd*w + b) @ W1 * dis   [128 -> 32] ----
__global__ __launch_bounds__(256) void k_norm_conv1(const float* __restrict__ x,
                                                    const int* __restrict__ startg,
                                                    const float* __restrict__ nw,
                                                    const float* __restrict__ nb,
                                                    const float* __restrict__ W1,
                                                    const float* __restrict__ dis,
                                                    float* __restrict__ p1) {
    __shared__ float sW[FIN * 32];    // 16 KB
    __shared__ float ssum[256], ssq[256];
    __shared__ float sscale[FIN], sshift[FIN];
    __shared__ float sx[8 * FIN];     // 4 KB
    int g = blockIdx.x;
    int s = startg[g], e = startg[g + 1];
    if (s == e) return;
    int t = threadIdx.x;
    const float4* W4 = (const float4*)W1;
    for (int i = t; i < FIN * 32 / 4; i += 256) ((float4*)sW)[i] = W4[i];
    // stats: 2 slots x 128 channels
    {
        int c = t & 127, slot = t >> 7;
        float sum = 0.f, sq = 0.f;
        for (int n = s + slot; n < e; n += 2) {
            float v = x[n * FIN + c];
            sum += v; sq += v * v;
        }
        ssum[t] = sum; ssq[t] = sq;
    }
    __syncthreads();
    if (t < 128) {
        float sm = ssum[t] + ssum[t + 128];
        float q2 = ssq[t] + ssq[t + 128];
        float cntf = (float)(e - s);
        float mean = sm / cntf;
        float var = q2 / cntf - mean * mean;
        float istd = rsqrtf(fmaxf(var, 0.f) + EPSV);
        float w = nw[0], b = nb[0];
        sscale[t] = istd * w;
        sshift[t] = b - mean * istd * w;
    }
    const float4* x4 = (const float4*)x;
    int k = t & 31, mslot = t >> 5;           // 8 node slots
    int row = t >> 5, c4 = t & 31;            // staging role
    for (int cb = s; cb < e; cb += 8) {
        __syncthreads();  // sscale ready (1st iter) / sx safe to overwrite
        int n = cb + row;
        if (n < e) {
            float4 xv = x4[n * 32 + c4];
            float4 r;
            r.x = xv.x * sscale[c4 * 4 + 0] + sshift[c4 * 4 + 0];
            r.y = xv.y * sscale[c4 * 4 + 1] + sshift[c4 * 4 + 1];
            r.z = xv.z * sscale[c4 * 4 + 2] + sshift[c4 * 4 + 2];
            r.w = xv.w * sscale[c4 * 4 + 3] + sshift[c4 * 4 + 3];
            ((float4*)sx)[row * 32 + c4] = r;
        }
        __syncthreads();
        int nm = cb + mslot;
        if (nm < e) {
            float acc = 0.f;
            for (int cc = 0; cc < FIN; ++cc) acc += sx[mslot * FIN + cc] * sW[cc * 32 + k];
            p1[nm * 32 + k] = acc * dis[nm];
        }
    }
}

// ---- gather1 (C=32, float4) + conv1 epilogue: p2 = relu(dis*(self+neigh)+b1)*dis ----
__global__ __launch_bounds__(256) void k_gather1(const float* __restrict__ p1,
                                                 const int* __restrict__ rowstart,
                                                 const int* __restrict__ csr,
                                                 const float* __restrict__ dis,
                                                 const float* __restrict__ b1,
                                                 float* __restrict__ p2) {
    int tid = blockIdx.x * 256 + threadIdx.x;  // NN*8 threads
    int n = tid >> 3, c4 = tid & 7;
    const float4* p1_4 = (const float4*)p1;
    int s = rowstart[n], e = rowstart[n + 1];
    float4 agg = p1_4[n * 8 + c4];  // self-loop (p = h*dis already)
    int j = s;
    for (; j + 1 < e; j += 2) {
        float4 v0 = p1_4[csr[j] * 8 + c4];
        float4 v1 = p1_4[csr[j + 1] * 8 + c4];
        agg.x += v0.x + v1.x; agg.y += v0.y + v1.y;
        agg.z += v0.z + v1.z; agg.w += v0.w + v1.w;
    }
    if (j < e) {
        float4 v = p1_4[csr[j] * 8 + c4];
        agg.x += v.x; agg.y += v.y; agg.z += v.z; agg.w += v.w;
    }
    float d = dis[n];
    float4 bb = ((const float4*)b1)[c4];
    float4 r;
    r.x = fmaxf(d * agg.x + bb.x, 0.f) * d;
    r.y = fmaxf(d * agg.y + bb.y, 0.f) * d;
    r.z = fmaxf(d * agg.z + bb.z, 0.f) * d;
    r.w = fmaxf(d * agg.w + bb.w, 0.f) * d;
    ((float4*)p2)[n * 8 + c4] = r;
}

// ---- fused gather2 + conv2: p3 = relu((dis*(self+neigh))@W2 + b2)*dis  [32->64], 16 nodes/block ----
__global__ __launch_bounds__(256) void k_conv2g(const float* __restrict__ p2,
                                                const int* __restrict__ rowstart,
                                                const int* __restrict__ csr,
                                                const float* __restrict__ dis,
                                                const float* __restrict__ W2,
                                                const float* __restrict__ b2v,
                                                float* __restrict__ p3) {
    __shared__ float sW[32 * 64];        // 8 KB
    __shared__ float4 spart[16 * 16];    // 16 nodes x 2 halves x 8 c4 = 4 KB
    __shared__ float sa[16 * 32];        // 2 KB
    int t = threadIdx.x;
    const float4* W4 = (const float4*)W2;
    for (int i = t; i < 32 * 64 / 4; i += 256) ((float4*)sW)[i] = W4[i];
    int base = blockIdx.x * 16;
    const float4* p2_4 = (const float4*)p2;
    {
        int node = t >> 4, c4 = t & 7, half = (t >> 3) & 1;
        int n = base + node;
        int s = rowstart[n], e = rowstart[n + 1];
        float4 agg = {0.f, 0.f, 0.f, 0.f};
        if (half == 0) {
            agg = p2_4[n * 8 + c4];  // self
            for (int j = s; j < e; j += 2) {
                float4 v = p2_4[csr[j] * 8 + c4];
                agg.x += v.x; agg.y += v.y; agg.z += v.z; agg.w += v.w;
            }
        } else {
            for (int j = s + 1; j < e; j += 2) {
                float4 v = p2_4[csr[j] * 8 + c4];
                agg.x += v.x; agg.y += v.y; agg.z += v.z; agg.w += v.w;
            }
        }
        spart[node * 16 + half * 8 + c4] = agg;
    }
    __syncthreads();
    if (t < 128) {
        int nd = t >> 3, cc = t & 7;
        float4 a = spart[nd * 16 + cc], b = spart[nd * 16 + 8 + cc];
        float d = dis[base + nd];
        float4 r;
        r.x = d * (a.x + b.x); r.y = d * (a.y + b.y);
        r.z = d * (a.z + b.z); r.w = d * (a.w + b.w);
        ((float4*)sa)[nd * 8 + cc] = r;
    }
    __syncthreads();
    int k = t & 63, grp = t >> 6;
    float acc[4] = {0.f, 0.f, 0.f, 0.f};
    for (int c = 0; c < 32; ++c) {
        float w = sW[c * 64 + k];
#pragma unroll
        for (int q = 0; q < 4; ++q) acc[q] += sa[(grp * 4 + q) * 32 + c] * w;
    }
    float bb = b2v[k];
#pragma unroll
    for (int q = 0; q < 4; ++q) {
        int n = base + grp * 4 + q;
        float h = fmaxf(acc[q] + bb, 0.f);
        p3[n * 64 + k] = h * dis[n];
    }
}

// ---- fused gather3 + conv3 + run-length pool: 64 contiguous nodes/block ----
__global__ __launch_bounds__(256) void k_conv3p(const float* __restrict__ p3,
                                                const int* __restrict__ rowstart,
                                                const int* __restrict__ csr,
                                                const float* __restrict__ dis,
                                                const float* __restrict__ W3,
                                                const float* __restrict__ b3v,
                                                const int* __restrict__ batch,
                                                unsigned int* __restrict__ pooled) {
    __shared__ float sW[64 * 128];   // 32 KB
    __shared__ float sa[64 * 64];    // 16 KB
    __shared__ int sbatch[64];
    int t = threadIdx.x;
    const float4* W4 = (const float4*)W3;
    for (int i = t; i < 64 * 128 / 4; i += 256) ((float4*)sW)[i] = W4[i];
    int base = blockIdx.x * 64;
    if (t < 64) sbatch[t] = batch[base + t];
    // gather: 4 threads per node, each handles 4 float4 (16 floats of 64)
    {
        int node = t >> 2, part = t & 3;
        int n = base + node;
        const float4* p3_4 = (const float4*)p3;
        int s = rowstart[n], e = rowstart[n + 1];
        float4 agg[4];
#pragma unroll
        for (int i = 0; i < 4; ++i) agg[i] = p3_4[n * 16 + part * 4 + i];  // self
        for (int j = s; j < e; ++j) {
            int sn = csr[j];
#pragma unroll
            for (int i = 0; i < 4; ++i) {
                float4 v = p3_4[sn * 16 + part * 4 + i];
                agg[i].x += v.x; agg[i].y += v.y; agg[i].z += v.z; agg[i].w += v.w;
            }
        }
        float dn = dis[n];
#pragma unroll
        for (int i = 0; i < 4; ++i) {
            float4 r;
            r.x = dn * agg[i].x; r.y = dn * agg[i].y;
            r.z = dn * agg[i].z; r.w = dn * agg[i].w;
            ((float4*)sa)[node * 16 + part * 4 + i] = r;
        }
    }
    __syncthreads();
    // matmul + run-length pooling over this thread's 32 contiguous nodes
    int k = t & 127, half = t >> 7;
    float bb = b3v[k];
    int curg = sbatch[half * 32];
    float curmax = 0.f;
    for (int nb = 0; nb < 8; ++nb) {
        float acc[4] = {0.f, 0.f, 0.f, 0.f};
        for (int c = 0; c < 64; ++c) {
            float w = sW[c * 128 + k];
            int rowbase = (half * 32 + nb * 4) * 64 + c;
#pragma unroll
            for (int q = 0; q < 4; ++q) acc[q] += sa[rowbase + q * 64] * w;
        }
#pragma unroll
        for (int q = 0; q < 4; ++q) {
            int nl = half * 32 + nb * 4 + q;
            int g = sbatch[nl];
            float o = fmaxf(acc[q] + bb, 0.f);
            if (g != curg) {
                atomicMax(&pooled[curg * 128 + k], __float_as_uint(curmax));
                curg = g;
                curmax = o;
            } else {
                curmax = fmaxf(curmax, o);
            }
        }
    }
    atomicMax(&pooled[curg * 128 + k], __float_as_uint(curmax));
}

// ---- lin1: mid = relu(pooled @ lin1_W + b), 8 graphs/block ----
__global__ __launch_bounds__(256) void k_lin1(const float* __restrict__ pooled,
                                              const float* __restrict__ W,
                                              const float* __restrict__ bias,
                                              float* __restrict__ mid) {
    __shared__ float sp[8 * 128];  // 4 KB
    int t = threadIdx.x;
    int base = blockIdx.x * 8;
    for (int i = t; i < 8 * 128; i += 256) sp[i] = pooled[base * 128 + i];
    __syncthreads();
    float acc[8] = {0.f, 0.f, 0.f, 0.f, 0.f, 0.f, 0.f, 0.f};
    for (int c = 0; c < 128; ++c) {
        float w = W[c * 256 + t];
#pragma unroll
        for (int gl = 0; gl < 8; ++gl) acc[gl] += sp[gl * 128 + c] * w;
    }
    float bb = bias[t];
#pragma unroll
    for (int gl = 0; gl < 8; ++gl) mid[(base + gl) * 256 + t] = fmaxf(acc[gl] + bb, 0.f);
}

// ---- lin2: out = mid @ lin2_W + b, 16 graphs/block ----
__global__ __launch_bounds__(128) void k_lin2(const float* __restrict__ mid,
                                              const float* __restrict__ W,
                                              const float* __restrict__ bias,
                                              float* __restrict__ out) {
    __shared__ float sm[16 * 256];  // 16 KB
    int t = threadIdx.x;
    int base = blockIdx.x * 16;
    for (int i = t; i < 16 * 256; i += 128) sm[i] = mid[base * 256 + i];
    __syncthreads();
    float acc[16];
#pragma unroll
    for (int i = 0; i < 16; ++i) acc[i] = 0.f;
    for (int c = 0; c < 256; ++c) {
        float w = W[c * 128 + t];
#pragma unroll
        for (int gl = 0; gl < 16; ++gl) acc[gl] += sm[gl * 256 + c] * w;
    }
    float bb = bias[t];
#pragma unroll
    for (int gl = 0; gl < 16; ++gl)
        out[(base + gl) * 128 + t] = acc[gl] + bb;
}

extern "C" void kernel_launch(void* const* d_in, const int* in_sizes, int n_in,
                              void* d_out, int out_size, void* d_ws, size_t ws_size,
                              hipStream_t stream) {
    (void)in_sizes; (void)n_in; (void)out_size; (void)ws_size;
    const float* x   = (const float*)d_in[0];
    const int* ei    = (const int*)d_in[1];
    const int* src = ei;
    const int* dst = ei + NE;
    const int* batch = (const int*)d_in[2];
    const float* nw  = (const float*)d_in[3];
    const float* nb  = (const float*)d_in[4];
    const float* W1  = (const float*)d_in[5];
    const float* b1  = (const float*)d_in[6];
    const float* W2  = (const float*)d_in[7];
    const float* b2  = (const float*)d_in[8];
    const float* W3  = (const float*)d_in[9];
    const float* b3  = (const float*)d_in[10];
    const float* l1W = (const float*)d_in[11];
    const float* l1b = (const float*)d_in[12];
    const float* l2W = (const float*)d_in[13];
    const float* l2b = (const float*)d_in[14];
    float* out = (float*)d_out;

    char* wsp = (char*)d_ws;
    int*   cnt      = (int*)wsp;   wsp += (size_t)NN * 4;        // becomes dis in place
    int*   rowstart = (int*)wsp;   wsp += (size_t)(NN + 1) * 4;
    int*   cursor   = (int*)wsp;   wsp += (size_t)NN * 4;
    int*   bsum     = (int*)wsp;   wsp += (size_t)NBS * 4;
    int*   bpre     = (int*)wsp;   wsp += (size_t)NBS * 4;
    int*   startg   = (int*)wsp;   wsp += (size_t)(NG + 1) * 4;
    int*   csr      = (int*)wsp;   wsp += (size_t)NE * 4;        // 3.2 MB
    wsp += ((256 - ((uintptr_t)wsp & 255)) & 255);
    float* pooled  = (float*)wsp; wsp += (size_t)NG * 128 * 4;   // 4 MB
    float* regionA = (float*)wsp; wsp += (size_t)NN * 64 * 4;    // p1|p2, later mid
    float* regionB = (float*)wsp; wsp += (size_t)NN * 64 * 4;    // p3

    float* dis  = (float*)cnt;  // in-place after k_dis
    float* p1   = regionA;
    float* p2   = regionA + (size_t)NN * 32;
    float* p3   = regionB;
    float* mid  = regionA;      // p1/p2 dead after k_conv2g

    // CSR prep
    hipMemsetAsync(cnt, 0, (size_t)NN * 4, stream);
    k_cnt<<<(NE + 255) / 256, 256, 0, stream>>>(dst, cnt);
    k_blocksum<<<NBS, 256, 0, stream>>>(cnt, bsum);
    k_scanb<<<1, 1024, 0, stream>>>(bsum, bpre);
    k_scanchunk<<<NBS, 256, 0, stream>>>(cnt, bpre, rowstart);
    k_dis<<<(NN + 255) / 256, 256, 0, stream>>>(cnt);  // cnt -> dis in place
    hipMemcpyAsync(cursor, rowstart, (size_t)NN * 4, hipMemcpyDeviceToDevice, stream);
    k_fill<<<(NE + 255) / 256, 256, 0, stream>>>(src, dst, cursor, csr);

    // layer 1
    k_starts<<<(NN + 255) / 256, 256, 0, stream>>>(batch, startg);
    k_norm_conv1<<<NG, 256, 0, stream>>>(x, startg, nw, nb, W1, dis, p1);
    k_gather1<<<NN * 8 / 256, 256, 0, stream>>>(p1, rowstart, csr, dis, b1, p2);
    // layer 2 (fused gather+matmul)
    k_conv2g<<<NN / 16, 256, 0, stream>>>(p2, rowstart, csr, dis, W2, b2, p3);
    // layer 3 (fused gather+matmul+pool over 64-node blocks, run-length atomics)
    hipMemsetAsync(pooled, 0, (size_t)NG * 128 * 4, stream);
    k_conv3p<<<NN / 64, 256, 0, stream>>>(p3, rowstart, csr, dis, W3, b3, batch,
                                          (unsigned int*)pooled);

    // head
    k_lin1<<<NG / 8, 256, 0, stream>>>(pooled, l1W, l1b, mid);
    k_lin2<<<NG / 16, 128, 0, stream>>>(mid, l2W, l2b, out);
}

// Round 6
// 700.360 us; speedup vs baseline: 1.0347x; 1.0347x over previous
//
#include <hip/hip_runtime.h>
#include <stdint.h>

#define NN 200000
#define NE 800000
#define FIN 128
#define NG 8000
#define EPSV 1e-5f
#define NBS ((NN + 255) / 256)   // 782 scan blocks

// ---- int degree histogram over dst ----
__global__ void k_cnt(const int* __restrict__ dst, int* __restrict__ cnt) {
    int e = blockIdx.x * 256 + threadIdx.x;
    if (e < NE) atomicAdd(&cnt[dst[e]], 1);
}

// ---- per-256-chunk sums ----
__global__ void k_blocksum(const int* __restrict__ cnt, int* __restrict__ bsum) {
    __shared__ int sh[256];
    int b = blockIdx.x, t = threadIdx.x;
    int idx = b * 256 + t;
    sh[t] = (idx < NN) ? cnt[idx] : 0;
    __syncthreads();
    for (int o = 128; o > 0; o >>= 1) {
        if (t < o) sh[t] += sh[t + o];
        __syncthreads();
    }
    if (t == 0) bsum[b] = sh[0];
}

// ---- single-block scan of chunk sums -> exclusive prefixes ----
__global__ __launch_bounds__(1024) void k_scanb(const int* __restrict__ bsum, int* __restrict__ bpre) {
    __shared__ int sh[1024];
    int t = threadIdx.x;
    int v = (t < NBS) ? bsum[t] : 0;
    sh[t] = v;
    __syncthreads();
    for (int o = 1; o < 1024; o <<= 1) {
        int add = (t >= o) ? sh[t - o] : 0;
        __syncthreads();
        sh[t] += add;
        __syncthreads();
    }
    if (t < NBS) bpre[t] = sh[t] - v;  // exclusive
}

// ---- per-chunk scan + offset -> rowstart (exclusive) ----
__global__ void k_scanchunk(const int* __restrict__ cnt, const int* __restrict__ bpre,
                            int* __restrict__ rowstart) {
    __shared__ int sh[256];
    int b = blockIdx.x, t = threadIdx.x;
    int idx = b * 256 + t;
    int v = (idx < NN) ? cnt[idx] : 0;
    sh[t] = v;
    __syncthreads();
    for (int o = 1; o < 256; o <<= 1) {
        int add = (t >= o) ? sh[t - o] : 0;
        __syncthreads();
        sh[t] += add;
        __syncthreads();
    }
    if (idx < NN) rowstart[idx] = bpre[b] + sh[t] - v;
    if (idx == 0) rowstart[NN] = NE;
}

// ---- dis = rsqrt(1+deg), IN PLACE over cnt (int -> float reinterpret) ----
__global__ void k_dis(int* __restrict__ cnt) {
    int n = blockIdx.x * 256 + threadIdx.x;
    if (n < NN) {
        float d = rsqrtf(1.0f + (float)cnt[n]);
        ((float*)cnt)[n] = d;
    }
}

// ---- fill CSR: csr[pos] = src, bucketed by dst ----
__global__ void k_fill(const int* __restrict__ src, const int* __restrict__ dst,
                       int* __restrict__ cursor, int* __restrict__ csr) {
    int e = blockIdx.x * 256 + threadIdx.x;
    if (e < NE) {
        int pos = atomicAdd(&cursor[dst[e]], 1);
        csr[pos] = src[e];
    }
}

// ---- graph start offsets from sorted batch ----
__global__ void k_starts(const int* __restrict__ batch, int* __restrict__ startg) {
    int n = blockIdx.x * 256 + threadIdx.x;
    if (n >= NN) return;
    int b = batch[n];
    int prev = (n == 0) ? -1 : batch[n - 1];
    for (int g = prev + 1; g <= b; ++g) startg[g] = n;
    if (n == NN - 1) {
        for (int g = b + 1; g <= NG; ++g) startg[g] = NN;
    }
}

// ---- fused instance-norm + conv1 (one block per graph):
//      p1 = ((x - mean)*istd*w + b) @ W1 * dis   [128 -> 32] ----
__global__ __launch_bounds__(256) void k_norm_conv1(const float* __restrict__ x,
                                                    const int* __restrict__ startg,
                                                    const float* __restrict__ nw,
                                                    const float* __restrict__ nb,
                                                    const float* __restrict__ W1,
                                                    const float* __restrict__ dis,
                                                    float* __restrict__ p1) {
    __shared__ float sW[FIN * 32];    // 16 KB
    __shared__ float ssum[256], ssq[256];
    __shared__ float sscale[FIN], sshift[FIN];
    __shared__ float sx[8 * FIN];     // 4 KB
    int g = blockIdx.x;
    int s = startg[g], e = startg[g + 1];
    if (s == e) return;
    int t = threadIdx.x;
    const float4* W4 = (const float4*)W1;
    for (int i = t; i < FIN * 32 / 4; i += 256) ((float4*)sW)[i] = W4[i];
    // stats: 2 slots x 128 channels
    {
        int c = t & 127, slot = t >> 7;
        float sum = 0.f, sq = 0.f;
        for (int n = s + slot; n < e; n += 2) {
            float v = x[n * FIN + c];
            sum += v; sq += v * v;
        }
        ssum[t] = sum; ssq[t] = sq;
    }
    __syncthreads();
    if (t < 128) {
        float sm = ssum[t] + ssum[t + 128];
        float q2 = ssq[t] + ssq[t + 128];
        float cntf = (float)(e - s);
        float mean = sm / cntf;
        float var = q2 / cntf - mean * mean;
        float istd = rsqrtf(fmaxf(var, 0.f) + EPSV);
        float w = nw[0], b = nb[0];
        sscale[t] = istd * w;
        sshift[t] = b - mean * istd * w;
    }
    const float4* x4 = (const float4*)x;
    int k = t & 31, mslot = t >> 5;           // 8 node slots
    int row = t >> 5, c4 = t & 31;            // staging role
    for (int cb = s; cb < e; cb += 8) {
        __syncthreads();  // sscale ready (1st iter) / sx safe to overwrite
        int n = cb + row;
        if (n < e) {
            float4 xv = x4[n * 32 + c4];
            float4 r;
            r.x = xv.x * sscale[c4 * 4 + 0] + sshift[c4 * 4 + 0];
            r.y = xv.y * sscale[c4 * 4 + 1] + sshift[c4 * 4 + 1];
            r.z = xv.z * sscale[c4 * 4 + 2] + sshift[c4 * 4 + 2];
            r.w = xv.w * sscale[c4 * 4 + 3] + sshift[c4 * 4 + 3];
            ((float4*)sx)[row * 32 + c4] = r;
        }
        __syncthreads();
        int nm = cb + mslot;
        if (nm < e) {
            float acc = 0.f;
            for (int cc = 0; cc < FIN; ++cc) acc += sx[mslot * FIN + cc] * sW[cc * 32 + k];
            p1[nm * 32 + k] = acc * dis[nm];
        }
    }
}

// ---- gather1 (C=32, float4) + conv1 epilogue: p2 = relu(dis*(self+neigh)+b1)*dis ----
__global__ __launch_bounds__(256) void k_gather1(const float* __restrict__ p1,
                                                 const int* __restrict__ rowstart,
                                                 const int* __restrict__ csr,
                                                 const float* __restrict__ dis,
                                                 const float* __restrict__ b1,
                                                 float* __restrict__ p2) {
    int tid = blockIdx.x * 256 + threadIdx.x;  // NN*8 threads
    int n = tid >> 3, c4 = tid & 7;
    const float4* p1_4 = (const float4*)p1;
    int s = rowstart[n], e = rowstart[n + 1];
    float4 agg = p1_4[n * 8 + c4];  // self-loop (p = h*dis already)
    int j = s;
    for (; j + 1 < e; j += 2) {
        float4 v0 = p1_4[csr[j] * 8 + c4];
        float4 v1 = p1_4[csr[j + 1] * 8 + c4];
        agg.x += v0.x + v1.x; agg.y += v0.y + v1.y;
        agg.z += v0.z + v1.z; agg.w += v0.w + v1.w;
    }
    if (j < e) {
        float4 v = p1_4[csr[j] * 8 + c4];
        agg.x += v.x; agg.y += v.y; agg.z += v.z; agg.w += v.w;
    }
    float d = dis[n];
    float4 bb = ((const float4*)b1)[c4];
    float4 r;
    r.x = fmaxf(d * agg.x + bb.x, 0.f) * d;
    r.y = fmaxf(d * agg.y + bb.y, 0.f) * d;
    r.z = fmaxf(d * agg.z + bb.z, 0.f) * d;
    r.w = fmaxf(d * agg.w + bb.w, 0.f) * d;
    ((float4*)p2)[n * 8 + c4] = r;
}

// ---- fused gather2 + conv2: p3 = relu((dis*(self+neigh))@W2 + b2)*dis  [32->64], 16 nodes/block ----
__global__ __launch_bounds__(256) void k_conv2g(const float* __restrict__ p2,
                                                const int* __restrict__ rowstart,
                                                const int* __restrict__ csr,
                                                const float* __restrict__ dis,
                                                const float* __restrict__ W2,
                                                const float* __restrict__ b2v,
                                                float* __restrict__ p3) {
    __shared__ float sW[32 * 64];        // 8 KB
    __shared__ float4 spart[16 * 16];    // 16 nodes x 2 halves x 8 c4 = 4 KB
    __shared__ float sa[16 * 32];        // 2 KB
    int t = threadIdx.x;
    const float4* W4 = (const float4*)W2;
    for (int i = t; i < 32 * 64 / 4; i += 256) ((float4*)sW)[i] = W4[i];
    int base = blockIdx.x * 16;
    const float4* p2_4 = (const float4*)p2;
    {
        int node = t >> 4, c4 = t & 7, half = (t >> 3) & 1;
        int n = base + node;
        int s = rowstart[n], e = rowstart[n + 1];
        float4 agg = {0.f, 0.f, 0.f, 0.f};
        if (half == 0) {
            agg = p2_4[n * 8 + c4];  // self
            for (int j = s; j < e; j += 2) {
                float4 v = p2_4[csr[j] * 8 + c4];
                agg.x += v.x; agg.y += v.y; agg.z += v.z; agg.w += v.w;
            }
        } else {
            for (int j = s + 1; j < e; j += 2) {
                float4 v = p2_4[csr[j] * 8 + c4];
                agg.x += v.x; agg.y += v.y; agg.z += v.z; agg.w += v.w;
            }
        }
        spart[node * 16 + half * 8 + c4] = agg;
    }
    __syncthreads();
    if (t < 128) {
        int nd = t >> 3, cc = t & 7;
        float4 a = spart[nd * 16 + cc], b = spart[nd * 16 + 8 + cc];
        float d = dis[base + nd];
        float4 r;
        r.x = d * (a.x + b.x); r.y = d * (a.y + b.y);
        r.z = d * (a.z + b.z); r.w = d * (a.w + b.w);
        ((float4*)sa)[nd * 8 + cc] = r;
    }
    __syncthreads();
    int k = t & 63, grp = t >> 6;
    float acc[4] = {0.f, 0.f, 0.f, 0.f};
    for (int c = 0; c < 32; ++c) {
        float w = sW[c * 64 + k];
#pragma unroll
        for (int q = 0; q < 4; ++q) acc[q] += sa[(grp * 4 + q) * 32 + c] * w;
    }
    float bb = b2v[k];
#pragma unroll
    for (int q = 0; q < 4; ++q) {
        int n = base + grp * 4 + q;
        float h = fmaxf(acc[q] + bb, 0.f);
        p3[n * 64 + k] = h * dis[n];
    }
}

// ---- gather3 (C=64, float4, 16 lanes/node): a3 = dis*(self+neigh) ----
__global__ __launch_bounds__(256) void k_gather3(const float* __restrict__ p3,
                                                 const int* __restrict__ rowstart,
                                                 const int* __restrict__ csr,
                                                 const float* __restrict__ dis,
                                                 float* __restrict__ a3) {
    int tid = blockIdx.x * 256 + threadIdx.x;  // NN*16 threads
    int n = tid >> 4, c4 = tid & 15;
    const float4* p3_4 = (const float4*)p3;
    int s = rowstart[n], e = rowstart[n + 1];
    float4 agg = p3_4[n * 16 + c4];  // self
    int j = s;
    for (; j + 1 < e; j += 2) {
        float4 v0 = p3_4[csr[j] * 16 + c4];
        float4 v1 = p3_4[csr[j + 1] * 16 + c4];
        agg.x += v0.x + v1.x; agg.y += v0.y + v1.y;
        agg.z += v0.z + v1.z; agg.w += v0.w + v1.w;
    }
    if (j < e) {
        float4 v = p3_4[csr[j] * 16 + c4];
        agg.x += v.x; agg.y += v.y; agg.z += v.z; agg.w += v.w;
    }
    float d = dis[n];
    float4 r;
    r.x = d * agg.x; r.y = d * agg.y; r.z = d * agg.z; r.w = d * agg.w;
    ((float4*)a3)[n * 16 + c4] = r;
}

// ---- conv3 + run-length max-pool: 64 contiguous nodes/block, coalesced a3 read ----
__global__ __launch_bounds__(256) void k_conv3r(const float* __restrict__ a3,
                                                const float* __restrict__ W3,
                                                const float* __restrict__ b3v,
                                                const int* __restrict__ batch,
                                                unsigned int* __restrict__ pooled) {
    __shared__ float sW[64 * 128];   // 32 KB
    __shared__ float sa[64 * 64];    // 16 KB
    __shared__ int sbatch[64];
    int t = threadIdx.x;
    const float4* W4 = (const float4*)W3;
    for (int i = t; i < 64 * 128 / 4; i += 256) ((float4*)sW)[i] = W4[i];
    int base = blockIdx.x * 64;
    if (t < 64) sbatch[t] = batch[base + t];
    const float4* a3_4 = (const float4*)a3;
    for (int i = t; i < 64 * 16; i += 256) ((float4*)sa)[i] = a3_4[(size_t)base * 16 + i];
    __syncthreads();
    int k = t & 127, half = t >> 7;  // each thread: 32 contiguous nodes x 1 output channel
    float bb = b3v[k];
    const float4* sa4 = (const float4*)sa;
    int curg = sbatch[half * 32];
    float curmax = 0.f;
    for (int nb = 0; nb < 8; ++nb) {
        int row0 = half * 32 + nb * 4;
        float acc0 = 0.f, acc1 = 0.f, acc2 = 0.f, acc3 = 0.f;
        for (int c4 = 0; c4 < 16; ++c4) {
            float4 a0 = sa4[(row0 + 0) * 16 + c4];
            float4 a1 = sa4[(row0 + 1) * 16 + c4];
            float4 a2 = sa4[(row0 + 2) * 16 + c4];
            float4 a3v = sa4[(row0 + 3) * 16 + c4];
            float w0 = sW[(c4 * 4 + 0) * 128 + k];
            float w1 = sW[(c4 * 4 + 1) * 128 + k];
            float w2 = sW[(c4 * 4 + 2) * 128 + k];
            float w3 = sW[(c4 * 4 + 3) * 128 + k];
            acc0 += a0.x * w0 + a0.y * w1 + a0.z * w2 + a0.w * w3;
            acc1 += a1.x * w0 + a1.y * w1 + a1.z * w2 + a1.w * w3;
            acc2 += a2.x * w0 + a2.y * w1 + a2.z * w2 + a2.w * w3;
            acc3 += a3v.x * w0 + a3v.y * w1 + a3v.z * w2 + a3v.w * w3;
        }
        float oq[4] = {acc0, acc1, acc2, acc3};
#pragma unroll
        for (int q = 0; q < 4; ++q) {
            int nl = row0 + q;
            int g = sbatch[nl];
            float o = fmaxf(oq[q] + bb, 0.f);
            if (g != curg) {
                atomicMax(&pooled[curg * 128 + k], __float_as_uint(curmax));
                curg = g;
                curmax = o;
            } else {
                curmax = fmaxf(curmax, o);
            }
        }
    }
    atomicMax(&pooled[curg * 128 + k], __float_as_uint(curmax));
}

// ---- lin1: mid = relu(pooled @ lin1_W + b), 8 graphs/block ----
__global__ __launch_bounds__(256) void k_lin1(const float* __restrict__ pooled,
                                              const float* __restrict__ W,
                                              const float* __restrict__ bias,
                                              float* __restrict__ mid) {
    __shared__ float sp[8 * 128];  // 4 KB
    int t = threadIdx.x;
    int base = blockIdx.x * 8;
    for (int i = t; i < 8 * 128; i += 256) sp[i] = pooled[base * 128 + i];
    __syncthreads();
    float acc[8] = {0.f, 0.f, 0.f, 0.f, 0.f, 0.f, 0.f, 0.f};
    for (int c = 0; c < 128; ++c) {
        float w = W[c * 256 + t];
#pragma unroll
        for (int gl = 0; gl < 8; ++gl) acc[gl] += sp[gl * 128 + c] * w;
    }
    float bb = bias[t];
#pragma unroll
    for (int gl = 0; gl < 8; ++gl) mid[(base + gl) * 256 + t] = fmaxf(acc[gl] + bb, 0.f);
}

// ---- lin2: out = mid @ lin2_W + b, 16 graphs/block ----
__global__ __launch_bounds__(128) void k_lin2(const float* __restrict__ mid,
                                              const float* __restrict__ W,
                                              const float* __restrict__ bias,
                                              float* __restrict__ out) {
    __shared__ float sm[16 * 256];  // 16 KB
    int t = threadIdx.x;
    int base = blockIdx.x * 16;
    for (int i = t; i < 16 * 256; i += 128) sm[i] = mid[base * 256 + i];
    __syncthreads();
    float acc[16];
#pragma unroll
    for (int i = 0; i < 16; ++i) acc[i] = 0.f;
    for (int c = 0; c < 256; ++c) {
        float w = W[c * 128 + t];
#pragma unroll
        for (int gl = 0; gl < 16; ++gl) acc[gl] += sm[gl * 256 + c] * w;
    }
    float bb = bias[t];
#pragma unroll
    for (int gl = 0; gl < 16; ++gl)
        out[(base + gl) * 128 + t] = acc[gl] + bb;
}

extern "C" void kernel_launch(void* const* d_in, const int* in_sizes, int n_in,
                              void* d_out, int out_size, void* d_ws, size_t ws_size,
                              hipStream_t stream) {
    (void)in_sizes; (void)n_in; (void)out_size; (void)ws_size;
    const float* x   = (const float*)d_in[0];
    const int* ei    = (const int*)d_in[1];
    const int* src = ei;
    const int* dst = ei + NE;
    const int* batch = (const int*)d_in[2];
    const float* nw  = (const float*)d_in[3];
    const float* nb  = (const float*)d_in[4];
    const float* W1  = (const float*)d_in[5];
    const float* b1  = (const float*)d_in[6];
    const float* W2  = (const float*)d_in[7];
    const float* b2  = (const float*)d_in[8];
    const float* W3  = (const float*)d_in[9];
    const float* b3  = (const float*)d_in[10];
    const float* l1W = (const float*)d_in[11];
    const float* l1b = (const float*)d_in[12];
    const float* l2W = (const float*)d_in[13];
    const float* l2b = (const float*)d_in[14];
    float* out = (float*)d_out;

    char* wsp = (char*)d_ws;
    int*   cnt      = (int*)wsp;   wsp += (size_t)NN * 4;        // becomes dis in place
    int*   rowstart = (int*)wsp;   wsp += (size_t)(NN + 1) * 4;
    int*   cursor   = (int*)wsp;   wsp += (size_t)NN * 4;
    int*   bsum     = (int*)wsp;   wsp += (size_t)NBS * 4;
    int*   bpre     = (int*)wsp;   wsp += (size_t)NBS * 4;
    int*   startg   = (int*)wsp;   wsp += (size_t)(NG + 1) * 4;
    int*   csr      = (int*)wsp;   wsp += (size_t)NE * 4;        // 3.2 MB
    wsp += ((256 - ((uintptr_t)wsp & 255)) & 255);
    float* pooled  = (float*)wsp; wsp += (size_t)NG * 128 * 4;   // 4 MB
    float* regionA = (float*)wsp; wsp += (size_t)NN * 64 * 4;    // p1|p2, later a3
    float* regionB = (float*)wsp; wsp += (size_t)NN * 64 * 4;    // p3, later mid

    float* dis  = (float*)cnt;  // in-place after k_dis
    float* p1   = regionA;
    float* p2   = regionA + (size_t)NN * 32;
    float* p3   = regionB;
    float* a3   = regionA;      // p1/p2 dead after k_conv2g
    float* mid  = regionB;      // p3 dead after k_gather3

    // CSR prep
    hipMemsetAsync(cnt, 0, (size_t)NN * 4, stream);
    k_cnt<<<(NE + 255) / 256, 256, 0, stream>>>(dst, cnt);
    k_blocksum<<<NBS, 256, 0, stream>>>(cnt, bsum);
    k_scanb<<<1, 1024, 0, stream>>>(bsum, bpre);
    k_scanchunk<<<NBS, 256, 0, stream>>>(cnt, bpre, rowstart);
    k_dis<<<(NN + 255) / 256, 256, 0, stream>>>(cnt);  // cnt -> dis in place
    hipMemcpyAsync(cursor, rowstart, (size_t)NN * 4, hipMemcpyDeviceToDevice, stream);
    k_fill<<<(NE + 255) / 256, 256, 0, stream>>>(src, dst, cursor, csr);

    // layer 1
    k_starts<<<(NN + 255) / 256, 256, 0, stream>>>(batch, startg);
    k_norm_conv1<<<NG, 256, 0, stream>>>(x, startg, nw, nb, W1, dis, p1);
    k_gather1<<<NN * 8 / 256, 256, 0, stream>>>(p1, rowstart, csr, dis, b1, p2);
    // layer 2 (fused gather+matmul)
    k_conv2g<<<NN / 16, 256, 0, stream>>>(p2, rowstart, csr, dis, W2, b2, p3);
    // layer 3 (separate gather, then matmul + run-length pool)
    k_gather3<<<NN * 16 / 256, 256, 0, stream>>>(p3, rowstart, csr, dis, a3);
    hipMemsetAsync(pooled, 0, (size_t)NG * 128 * 4, stream);
    k_conv3r<<<NN / 64, 256, 0, stream>>>(a3, W3, b3, batch, (unsigned int*)pooled);

    // head
    k_lin1<<<NG / 8, 256, 0, stream>>>(pooled, l1W, l1b, mid);
    k_lin2<<<NG / 16, 128, 0, stream>>>(mid, l2W, l2b, out);
}

// Round 7
// 584.164 us; speedup vs baseline: 1.2405x; 1.1989x over previous
//
#include <hip/hip_runtime.h>
#include <stdint.h>

#define NN 200000
#define NE 800000
#define FIN 128
#define NG 8000
#define EPSV 1e-5f
#define NBS ((NN + 255) / 256)   // 782 scan blocks

// ---- int degree histogram over dst ----
__global__ void k_cnt(const int* __restrict__ dst, int* __restrict__ cnt) {
    int e = blockIdx.x * 256 + threadIdx.x;
    if (e < NE) atomicAdd(&cnt[dst[e]], 1);
}

// ---- per-256-chunk sums ----
__global__ void k_blocksum(const int* __restrict__ cnt, int* __restrict__ bsum) {
    __shared__ int sh[256];
    int b = blockIdx.x, t = threadIdx.x;
    int idx = b * 256 + t;
    sh[t] = (idx < NN) ? cnt[idx] : 0;
    __syncthreads();
    for (int o = 128; o > 0; o >>= 1) {
        if (t < o) sh[t] += sh[t + o];
        __syncthreads();
    }
    if (t == 0) bsum[b] = sh[0];
}

// ---- single-block scan of chunk sums -> exclusive prefixes ----
__global__ __launch_bounds__(1024) void k_scanb(const int* __restrict__ bsum, int* __restrict__ bpre) {
    __shared__ int sh[1024];
    int t = threadIdx.x;
    int v = (t < NBS) ? bsum[t] : 0;
    sh[t] = v;
    __syncthreads();
    for (int o = 1; o < 1024; o <<= 1) {
        int add = (t >= o) ? sh[t - o] : 0;
        __syncthreads();
        sh[t] += add;
        __syncthreads();
    }
    if (t < NBS) bpre[t] = sh[t] - v;  // exclusive
}

// ---- per-chunk scan + offset -> rowstart (exclusive) ----
__global__ void k_scanchunk(const int* __restrict__ cnt, const int* __restrict__ bpre,
                            int* __restrict__ rowstart) {
    __shared__ int sh[256];
    int b = blockIdx.x, t = threadIdx.x;
    int idx = b * 256 + t;
    int v = (idx < NN) ? cnt[idx] : 0;
    sh[t] = v;
    __syncthreads();
    for (int o = 1; o < 256; o <<= 1) {
        int add = (t >= o) ? sh[t - o] : 0;
        __syncthreads();
        sh[t] += add;
        __syncthreads();
    }
    if (idx < NN) rowstart[idx] = bpre[b] + sh[t] - v;
    if (idx == 0) rowstart[NN] = NE;
}

// ---- dis = rsqrt(1+deg), IN PLACE over cnt (int -> float reinterpret) ----
__global__ void k_dis(int* __restrict__ cnt) {
    int n = blockIdx.x * 256 + threadIdx.x;
    if (n < NN) {
        float d = rsqrtf(1.0f + (float)cnt[n]);
        ((float*)cnt)[n] = d;
    }
}

// ---- fill CSR: csr[pos] = src, bucketed by dst ----
__global__ void k_fill(const int* __restrict__ src, const int* __restrict__ dst,
                       int* __restrict__ cursor, int* __restrict__ csr) {
    int e = blockIdx.x * 256 + threadIdx.x;
    if (e < NE) {
        int pos = atomicAdd(&cursor[dst[e]], 1);
        csr[pos] = src[e];
    }
}

// ---- graph start offsets from sorted batch ----
__global__ void k_starts(const int* __restrict__ batch, int* __restrict__ startg) {
    int n = blockIdx.x * 256 + threadIdx.x;
    if (n >= NN) return;
    int b = batch[n];
    int prev = (n == 0) ? -1 : batch[n - 1];
    for (int g = prev + 1; g <= b; ++g) startg[g] = n;
    if (n == NN - 1) {
        for (int g = b + 1; g <= NG; ++g) startg[g] = NN;
    }
}

// ---- fused instance-norm + conv1 (one block per graph):
//      p1 = ((x - mean)*istd*w + b) @ W1 * dis   [128 -> 32] ----
__global__ __launch_bounds__(256) void k_norm_conv1(const float* __restrict__ x,
                                                    const int* __restrict__ startg,
                                                    const float* __restrict__ nw,
                                                    const float* __restrict__ nb,
                                                    const float* __restrict__ W1,
                                                    const float* __restrict__ dis,
                                                    float* __restrict__ p1) {
    __shared__ float sW[FIN * 32];    // 16 KB
    __shared__ float ssum[256], ssq[256];
    __shared__ float sscale[FIN], sshift[FIN];
    __shared__ float sx[8 * FIN];     // 4 KB
    int g = blockIdx.x;
    int s = startg[g], e = startg[g + 1];
    if (s == e) return;
    int t = threadIdx.x;
    const float4* W4 = (const float4*)W1;
    for (int i = t; i < FIN * 32 / 4; i += 256) ((float4*)sW)[i] = W4[i];
    // stats: 2 slots x 128 channels
    {
        int c = t & 127, slot = t >> 7;
        float sum = 0.f, sq = 0.f;
        for (int n = s + slot; n < e; n += 2) {
            float v = x[n * FIN + c];
            sum += v; sq += v * v;
        }
        ssum[t] = sum; ssq[t] = sq;
    }
    __syncthreads();
    if (t < 128) {
        float sm = ssum[t] + ssum[t + 128];
        float q2 = ssq[t] + ssq[t + 128];
        float cntf = (float)(e - s);
        float mean = sm / cntf;
        float var = q2 / cntf - mean * mean;
        float istd = rsqrtf(fmaxf(var, 0.f) + EPSV);
        float w = nw[0], b = nb[0];
        sscale[t] = istd * w;
        sshift[t] = b - mean * istd * w;
    }
    const float4* x4 = (const float4*)x;
    int k = t & 31, mslot = t >> 5;           // 8 node slots
    int row = t >> 5, c4 = t & 31;            // staging role
    for (int cb = s; cb < e; cb += 8) {
        __syncthreads();  // sscale ready (1st iter) / sx safe to overwrite
        int n = cb + row;
        if (n < e) {
            float4 xv = x4[n * 32 + c4];
            float4 r;
            r.x = xv.x * sscale[c4 * 4 + 0] + sshift[c4 * 4 + 0];
            r.y = xv.y * sscale[c4 * 4 + 1] + sshift[c4 * 4 + 1];
            r.z = xv.z * sscale[c4 * 4 + 2] + sshift[c4 * 4 + 2];
            r.w = xv.w * sscale[c4 * 4 + 3] + sshift[c4 * 4 + 3];
            ((float4*)sx)[row * 32 + c4] = r;
        }
        __syncthreads();
        int nm = cb + mslot;
        if (nm < e) {
            float acc = 0.f;
            for (int cc = 0; cc < FIN; ++cc) acc += sx[mslot * FIN + cc] * sW[cc * 32 + k];
            p1[nm * 32 + k] = acc * dis[nm];
        }
    }
}

// ---- gather1 (C=32, float4) + conv1 epilogue: p2 = relu(dis*(self+neigh)+b1)*dis ----
__global__ __launch_bounds__(256) void k_gather1(const float* __restrict__ p1,
                                                 const int* __restrict__ rowstart,
                                                 const int* __restrict__ csr,
                                                 const float* __restrict__ dis,
                                                 const float* __restrict__ b1,
                                                 float* __restrict__ p2) {
    int tid = blockIdx.x * 256 + threadIdx.x;  // NN*8 threads
    int n = tid >> 3, c4 = tid & 7;
    const float4* p1_4 = (const float4*)p1;
    int s = rowstart[n], e = rowstart[n + 1];
    float4 agg = p1_4[n * 8 + c4];  // self-loop (p = h*dis already)
    int j = s;
    for (; j + 1 < e; j += 2) {
        float4 v0 = p1_4[csr[j] * 8 + c4];
        float4 v1 = p1_4[csr[j + 1] * 8 + c4];
        agg.x += v0.x + v1.x; agg.y += v0.y + v1.y;
        agg.z += v0.z + v1.z; agg.w += v0.w + v1.w;
    }
    if (j < e) {
        float4 v = p1_4[csr[j] * 8 + c4];
        agg.x += v.x; agg.y += v.y; agg.z += v.z; agg.w += v.w;
    }
    float d = dis[n];
    float4 bb = ((const float4*)b1)[c4];
    float4 r;
    r.x = fmaxf(d * agg.x + bb.x, 0.f) * d;
    r.y = fmaxf(d * agg.y + bb.y, 0.f) * d;
    r.z = fmaxf(d * agg.z + bb.z, 0.f) * d;
    r.w = fmaxf(d * agg.w + bb.w, 0.f) * d;
    ((float4*)p2)[n * 8 + c4] = r;
}

// ---- fused gather2 + conv2: p3 = relu((dis*(self+neigh))@W2 + b2)*dis  [32->64], 16 nodes/block ----
__global__ __launch_bounds__(256) void k_conv2g(const float* __restrict__ p2,
                                                const int* __restrict__ rowstart,
                                                const int* __restrict__ csr,
                                                const float* __restrict__ dis,
                                                const float* __restrict__ W2,
                                                const float* __restrict__ b2v,
                                                float* __restrict__ p3) {
    __shared__ float sW[32 * 64];        // 8 KB
    __shared__ float4 spart[16 * 16];    // 16 nodes x 2 halves x 8 c4 = 4 KB
    __shared__ float sa[16 * 32];        // 2 KB
    int t = threadIdx.x;
    const float4* W4 = (const float4*)W2;
    for (int i = t; i < 32 * 64 / 4; i += 256) ((float4*)sW)[i] = W4[i];
    int base = blockIdx.x * 16;
    const float4* p2_4 = (const float4*)p2;
    {
        int node = t >> 4, c4 = t & 7, half = (t >> 3) & 1;
        int n = base + node;
        int s = rowstart[n], e = rowstart[n + 1];
        float4 agg = {0.f, 0.f, 0.f, 0.f};
        if (half == 0) {
            agg = p2_4[n * 8 + c4];  // self
            for (int j = s; j < e; j += 2) {
                float4 v = p2_4[csr[j] * 8 + c4];
                agg.x += v.x; agg.y += v.y; agg.z += v.z; agg.w += v.w;
            }
        } else {
            for (int j = s + 1; j < e; j += 2) {
                float4 v = p2_4[csr[j] * 8 + c4];
                agg.x += v.x; agg.y += v.y; agg.z += v.z; agg.w += v.w;
            }
        }
        spart[node * 16 + half * 8 + c4] = agg;
    }
    __syncthreads();
    if (t < 128) {
        int nd = t >> 3, cc = t & 7;
        float4 a = spart[nd * 16 + cc], b = spart[nd * 16 + 8 + cc];
        float d = dis[base + nd];
        float4 r;
        r.x = d * (a.x + b.x); r.y = d * (a.y + b.y);
        r.z = d * (a.z + b.z); r.w = d * (a.w + b.w);
        ((float4*)sa)[nd * 8 + cc] = r;
    }
    __syncthreads();
    int k = t & 63, grp = t >> 6;
    float acc[4] = {0.f, 0.f, 0.f, 0.f};
    for (int c = 0; c < 32; ++c) {
        float w = sW[c * 64 + k];
#pragma unroll
        for (int q = 0; q < 4; ++q) acc[q] += sa[(grp * 4 + q) * 32 + c] * w;
    }
    float bb = b2v[k];
#pragma unroll
    for (int q = 0; q < 4; ++q) {
        int n = base + grp * 4 + q;
        float h = fmaxf(acc[q] + bb, 0.f);
        p3[n * 64 + k] = h * dis[n];
    }
}

// ---- gather3 (C=64, float4, 16 lanes/node): a3 = dis*(self+neigh) ----
__global__ __launch_bounds__(256) void k_gather3(const float* __restrict__ p3,
                                                 const int* __restrict__ rowstart,
                                                 const int* __restrict__ csr,
                                                 const float* __restrict__ dis,
                                                 float* __restrict__ a3) {
    int tid = blockIdx.x * 256 + threadIdx.x;  // NN*16 threads
    int n = tid >> 4, c4 = tid & 15;
    const float4* p3_4 = (const float4*)p3;
    int s = rowstart[n], e = rowstart[n + 1];
    float4 agg = p3_4[n * 16 + c4];  // self
    int j = s;
    for (; j + 1 < e; j += 2) {
        float4 v0 = p3_4[csr[j] * 16 + c4];
        float4 v1 = p3_4[csr[j + 1] * 16 + c4];
        agg.x += v0.x + v1.x; agg.y += v0.y + v1.y;
        agg.z += v0.z + v1.z; agg.w += v0.w + v1.w;
    }
    if (j < e) {
        float4 v = p3_4[csr[j] * 16 + c4];
        agg.x += v.x; agg.y += v.y; agg.z += v.z; agg.w += v.w;
    }
    float d = dis[n];
    float4 r;
    r.x = d * agg.x; r.y = d * agg.y; r.z = d * agg.z; r.w = d * agg.w;
    ((float4*)a3)[n * 16 + c4] = r;
}

// ---- conv3 + run-length max-pool: 64 nodes/block, 8-node x 4-channel register tiles ----
__global__ __launch_bounds__(256) void k_conv3t(const float* __restrict__ a3,
                                                const float* __restrict__ W3,
                                                const float* __restrict__ b3v,
                                                const int* __restrict__ batch,
                                                unsigned int* __restrict__ pooled) {
    __shared__ float sW[64 * 128];   // 32 KB
    __shared__ float sa[64 * 64];    // 16 KB
    __shared__ int sbatch[64];
    int t = threadIdx.x;
    const float4* W4 = (const float4*)W3;
    for (int i = t; i < 64 * 128 / 4; i += 256) ((float4*)sW)[i] = W4[i];
    int base = blockIdx.x * 64;
    if (t < 64) sbatch[t] = batch[base + t];
    const float4* a3_4 = (const float4*)a3;
    for (int i = t; i < 64 * 16; i += 256) ((float4*)sa)[i] = a3_4[(size_t)base * 16 + i];
    __syncthreads();
    int k0 = (t & 31) * 4;   // 4 consecutive output channels
    int n0 = (t >> 5) * 8;   // 8 consecutive nodes
    float acc[8][4];
#pragma unroll
    for (int i = 0; i < 8; ++i)
#pragma unroll
        for (int j = 0; j < 4; ++j) acc[i][j] = 0.f;
    const float4* sa4 = (const float4*)sa;
    for (int c4 = 0; c4 < 16; ++c4) {
        float4 w0 = *(const float4*)&sW[(c4 * 4 + 0) * 128 + k0];
        float4 w1 = *(const float4*)&sW[(c4 * 4 + 1) * 128 + k0];
        float4 w2 = *(const float4*)&sW[(c4 * 4 + 2) * 128 + k0];
        float4 w3 = *(const float4*)&sW[(c4 * 4 + 3) * 128 + k0];
#pragma unroll
        for (int i = 0; i < 8; ++i) {
            float4 a = sa4[(n0 + i) * 16 + c4];
            acc[i][0] += a.x * w0.x + a.y * w1.x + a.z * w2.x + a.w * w3.x;
            acc[i][1] += a.x * w0.y + a.y * w1.y + a.z * w2.y + a.w * w3.y;
            acc[i][2] += a.x * w0.z + a.y * w1.z + a.z * w2.z + a.w * w3.z;
            acc[i][3] += a.x * w0.w + a.y * w1.w + a.z * w2.w + a.w * w3.w;
        }
    }
    float4 bb = *(const float4*)&b3v[k0];
    float bbv[4] = {bb.x, bb.y, bb.z, bb.w};
    // run-length pool over this thread's 8 contiguous nodes, 4 channels
    int curg = sbatch[n0];
    float cm[4] = {0.f, 0.f, 0.f, 0.f};
#pragma unroll
    for (int i = 0; i < 8; ++i) {
        int g = sbatch[n0 + i];
        if (g != curg) {
#pragma unroll
            for (int j = 0; j < 4; ++j) {
                atomicMax(&pooled[curg * 128 + k0 + j], __float_as_uint(cm[j]));
                cm[j] = 0.f;
            }
            curg = g;
        }
#pragma unroll
        for (int j = 0; j < 4; ++j)
            cm[j] = fmaxf(cm[j], fmaxf(acc[i][j] + bbv[j], 0.f));
    }
#pragma unroll
    for (int j = 0; j < 4; ++j)
        atomicMax(&pooled[curg * 128 + k0 + j], __float_as_uint(cm[j]));
}

// ---- lin1: mid = relu(pooled @ lin1_W + b), 8 graphs/block ----
__global__ __launch_bounds__(256) void k_lin1(const float* __restrict__ pooled,
                                              const float* __restrict__ W,
                                              const float* __restrict__ bias,
                                              float* __restrict__ mid) {
    __shared__ float sp[8 * 128];  // 4 KB
    int t = threadIdx.x;
    int base = blockIdx.x * 8;
    for (int i = t; i < 8 * 128; i += 256) sp[i] = pooled[base * 128 + i];
    __syncthreads();
    float acc[8] = {0.f, 0.f, 0.f, 0.f, 0.f, 0.f, 0.f, 0.f};
    for (int c = 0; c < 128; ++c) {
        float w = W[c * 256 + t];
#pragma unroll
        for (int gl = 0; gl < 8; ++gl) acc[gl] += sp[gl * 128 + c] * w;
    }
    float bb = bias[t];
#pragma unroll
    for (int gl = 0; gl < 8; ++gl) mid[(base + gl) * 256 + t] = fmaxf(acc[gl] + bb, 0.f);
}

// ---- lin2: out = mid @ lin2_W + b, 16 graphs/block ----
__global__ __launch_bounds__(128) void k_lin2(const float* __restrict__ mid,
                                              const float* __restrict__ W,
                                              const float* __restrict__ bias,
                                              float* __restrict__ out) {
    __shared__ float sm[16 * 256];  // 16 KB
    int t = threadIdx.x;
    int base = blockIdx.x * 16;
    for (int i = t; i < 16 * 256; i += 128) sm[i] = mid[base * 256 + i];
    __syncthreads();
    float acc[16];
#pragma unroll
    for (int i = 0; i < 16; ++i) acc[i] = 0.f;
    for (int c = 0; c < 256; ++c) {
        float w = W[c * 128 + t];
#pragma unroll
        for (int gl = 0; gl < 16; ++gl) acc[gl] += sm[gl * 256 + c] * w;
    }
    float bb = bias[t];
#pragma unroll
    for (int gl = 0; gl < 16; ++gl)
        out[(base + gl) * 128 + t] = acc[gl] + bb;
}

extern "C" void kernel_launch(void* const* d_in, const int* in_sizes, int n_in,
                              void* d_out, int out_size, void* d_ws, size_t ws_size,
                              hipStream_t stream) {
    (void)in_sizes; (void)n_in; (void)out_size; (void)ws_size;
    const float* x   = (const float*)d_in[0];
    const int* ei    = (const int*)d_in[1];
    const int* src = ei;
    const int* dst = ei + NE;
    const int* batch = (const int*)d_in[2];
    const float* nw  = (const float*)d_in[3];
    const float* nb  = (const float*)d_in[4];
    const float* W1  = (const float*)d_in[5];
    const float* b1  = (const float*)d_in[6];
    const float* W2  = (const float*)d_in[7];
    const float* b2  = (const float*)d_in[8];
    const float* W3  = (const float*)d_in[9];
    const float* b3  = (const float*)d_in[10];
    const float* l1W = (const float*)d_in[11];
    const float* l1b = (const float*)d_in[12];
    const float* l2W = (const float*)d_in[13];
    const float* l2b = (const float*)d_in[14];
    float* out = (float*)d_out;

    char* wsp = (char*)d_ws;
    int*   cnt      = (int*)wsp;   wsp += (size_t)NN * 4;        // becomes dis in place
    int*   rowstart = (int*)wsp;   wsp += (size_t)(NN + 1) * 4;
    int*   cursor   = (int*)wsp;   wsp += (size_t)NN * 4;
    int*   bsum     = (int*)wsp;   wsp += (size_t)NBS * 4;
    int*   bpre     = (int*)wsp;   wsp += (size_t)NBS * 4;
    int*   startg   = (int*)wsp;   wsp += (size_t)(NG + 1) * 4;
    int*   csr      = (int*)wsp;   wsp += (size_t)NE * 4;        // 3.2 MB
    wsp += ((256 - ((uintptr_t)wsp & 255)) & 255);
    float* pooled  = (float*)wsp; wsp += (size_t)NG * 128 * 4;   // 4 MB
    float* regionA = (float*)wsp; wsp += (size_t)NN * 64 * 4;    // p1|p2, later a3
    float* regionB = (float*)wsp; wsp += (size_t)NN * 64 * 4;    // p3, later mid

    float* dis  = (float*)cnt;  // in-place after k_dis
    float* p1   = regionA;
    float* p2   = regionA + (size_t)NN * 32;
    float* p3   = regionB;
    float* a3   = regionA;      // p1/p2 dead after k_conv2g
    float* mid  = regionB;      // p3 dead after k_gather3

    // CSR prep
    hipMemsetAsync(cnt, 0, (size_t)NN * 4, stream);
    k_cnt<<<(NE + 255) / 256, 256, 0, stream>>>(dst, cnt);
    k_blocksum<<<NBS, 256, 0, stream>>>(cnt, bsum);
    k_scanb<<<1, 1024, 0, stream>>>(bsum, bpre);
    k_scanchunk<<<NBS, 256, 0, stream>>>(cnt, bpre, rowstart);
    k_dis<<<(NN + 255) / 256, 256, 0, stream>>>(cnt);  // cnt -> dis in place
    hipMemcpyAsync(cursor, rowstart, (size_t)NN * 4, hipMemcpyDeviceToDevice, stream);
    k_fill<<<(NE + 255) / 256, 256, 0, stream>>>(src, dst, cursor, csr);

    // layer 1
    k_starts<<<(NN + 255) / 256, 256, 0, stream>>>(batch, startg);
    k_norm_conv1<<<NG, 256, 0, stream>>>(x, startg, nw, nb, W1, dis, p1);
    k_gather1<<<NN * 8 / 256, 256, 0, stream>>>(p1, rowstart, csr, dis, b1, p2);
    // layer 2 (fused gather+matmul)
    k_conv2g<<<NN / 16, 256, 0, stream>>>(p2, rowstart, csr, dis, W2, b2, p3);
    // layer 3 (separate gather, then register-tiled matmul + run-length pool)
    k_gather3<<<NN * 16 / 256, 256, 0, stream>>>(p3, rowstart, csr, dis, a3);
    hipMemsetAsync(pooled, 0, (size_t)NG * 128 * 4, stream);
    k_conv3t<<<NN / 64, 256, 0, stream>>>(a3, W3, b3, batch, (unsigned int*)pooled);

    // head
    k_lin1<<<NG / 8, 256, 0, stream>>>(pooled, l1W, l1b, mid);
    k_lin2<<<NG / 16, 128, 0, stream>>>(mid, l2W, l2b, out);
}

// Round 8
// 573.706 us; speedup vs baseline: 1.2632x; 1.0182x over previous
//
#include <hip/hip_runtime.h>
#include <stdint.h>

#define NN 200000
#define NE 800000
#define FIN 128
#define NG 8000
#define EPSV 1e-5f
#define NBS ((NN + 255) / 256)   // 782 scan blocks

// ---- int degree histogram over dst ----
__global__ void k_cnt(const int* __restrict__ dst, int* __restrict__ cnt) {
    int e = blockIdx.x * 256 + threadIdx.x;
    if (e < NE) atomicAdd(&cnt[dst[e]], 1);
}

// ---- per-256-chunk sums ----
__global__ void k_blocksum(const int* __restrict__ cnt, int* __restrict__ bsum) {
    __shared__ int sh[256];
    int b = blockIdx.x, t = threadIdx.x;
    int idx = b * 256 + t;
    sh[t] = (idx < NN) ? cnt[idx] : 0;
    __syncthreads();
    for (int o = 128; o > 0; o >>= 1) {
        if (t < o) sh[t] += sh[t + o];
        __syncthreads();
    }
    if (t == 0) bsum[b] = sh[0];
}

// ---- single-block scan of chunk sums -> exclusive prefixes ----
__global__ __launch_bounds__(1024) void k_scanb(const int* __restrict__ bsum, int* __restrict__ bpre) {
    __shared__ int sh[1024];
    int t = threadIdx.x;
    int v = (t < NBS) ? bsum[t] : 0;
    sh[t] = v;
    __syncthreads();
    for (int o = 1; o < 1024; o <<= 1) {
        int add = (t >= o) ? sh[t - o] : 0;
        __syncthreads();
        sh[t] += add;
        __syncthreads();
    }
    if (t < NBS) bpre[t] = sh[t] - v;  // exclusive
}

// ---- per-chunk scan + offset -> rowstart (exclusive) ----
__global__ void k_scanchunk(const int* __restrict__ cnt, const int* __restrict__ bpre,
                            int* __restrict__ rowstart) {
    __shared__ int sh[256];
    int b = blockIdx.x, t = threadIdx.x;
    int idx = b * 256 + t;
    int v = (idx < NN) ? cnt[idx] : 0;
    sh[t] = v;
    __syncthreads();
    for (int o = 1; o < 256; o <<= 1) {
        int add = (t >= o) ? sh[t - o] : 0;
        __syncthreads();
        sh[t] += add;
        __syncthreads();
    }
    if (idx < NN) rowstart[idx] = bpre[b] + sh[t] - v;
    if (idx == 0) rowstart[NN] = NE;
}

// ---- dis = rsqrt(1+deg), IN PLACE over cnt (int -> float reinterpret) ----
__global__ void k_dis(int* __restrict__ cnt) {
    int n = blockIdx.x * 256 + threadIdx.x;
    if (n < NN) {
        float d = rsqrtf(1.0f + (float)cnt[n]);
        ((float*)cnt)[n] = d;
    }
}

// ---- fill CSR: csr[pos] = src, bucketed by dst ----
__global__ void k_fill(const int* __restrict__ src, const int* __restrict__ dst,
                       int* __restrict__ cursor, int* __restrict__ csr) {
    int e = blockIdx.x * 256 + threadIdx.x;
    if (e < NE) {
        int pos = atomicAdd(&cursor[dst[e]], 1);
        csr[pos] = src[e];
    }
}

// ---- graph start offsets from sorted batch ----
__global__ void k_starts(const int* __restrict__ batch, int* __restrict__ startg) {
    int n = blockIdx.x * 256 + threadIdx.x;
    if (n >= NN) return;
    int b = batch[n];
    int prev = (n == 0) ? -1 : batch[n - 1];
    for (int g = prev + 1; g <= b; ++g) startg[g] = n;
    if (n == NN - 1) {
        for (int g = b + 1; g <= NG; ++g) startg[g] = NN;
    }
}

// ---- per-graph instance-norm stats, latency-tolerant: 8 node slots x 32 float4 lanes ----
__global__ __launch_bounds__(256) void k_stats2(const float* __restrict__ x,
                                                const int* __restrict__ startg,
                                                const float* __restrict__ nw,
                                                const float* __restrict__ nb,
                                                float* __restrict__ scale,
                                                float* __restrict__ shift) {
    __shared__ float4 rsum[256], rsq[256];
    int g = blockIdx.x;
    int s = startg[g], e = startg[g + 1];
    if (s == e) return;
    int t = threadIdx.x;
    int slot = t >> 5, c4 = t & 31;
    const float4* x4 = (const float4*)x;
    float4 sum = {0.f, 0.f, 0.f, 0.f}, sq = {0.f, 0.f, 0.f, 0.f};
    for (int n = s + slot; n < e; n += 8) {
        float4 v = x4[n * 32 + c4];
        sum.x += v.x; sum.y += v.y; sum.z += v.z; sum.w += v.w;
        sq.x += v.x * v.x; sq.y += v.y * v.y; sq.z += v.z * v.z; sq.w += v.w * v.w;
    }
    rsum[slot * 32 + c4] = sum;
    rsq[slot * 32 + c4] = sq;
    __syncthreads();
    if (t < 32) {
        float4 S = rsum[t], Q = rsq[t];
#pragma unroll
        for (int sl = 1; sl < 8; ++sl) {
            float4 a = rsum[sl * 32 + t], b = rsq[sl * 32 + t];
            S.x += a.x; S.y += a.y; S.z += a.z; S.w += a.w;
            Q.x += b.x; Q.y += b.y; Q.z += b.z; Q.w += b.w;
        }
        float inv = 1.0f / (float)(e - s);
        float w = nw[0], b = nb[0];
        float4 sc, sh;
        {
            float m = S.x * inv, v = fmaxf(Q.x * inv - m * m, 0.f);
            float is = rsqrtf(v + EPSV); sc.x = is * w; sh.x = b - m * is * w;
        }
        {
            float m = S.y * inv, v = fmaxf(Q.y * inv - m * m, 0.f);
            float is = rsqrtf(v + EPSV); sc.y = is * w; sh.y = b - m * is * w;
        }
        {
            float m = S.z * inv, v = fmaxf(Q.z * inv - m * m, 0.f);
            float is = rsqrtf(v + EPSV); sc.z = is * w; sh.z = b - m * is * w;
        }
        {
            float m = S.w * inv, v = fmaxf(Q.w * inv - m * m, 0.f);
            float is = rsqrtf(v + EPSV); sc.w = is * w; sh.w = b - m * is * w;
        }
        ((float4*)scale)[g * 32 + t] = sc;
        ((float4*)shift)[g * 32 + t] = sh;
    }
}

// ---- conv1, register-tiled: 128 contiguous nodes/block, 4-node x 4-ch tiles
//      p1 = ((x*scale+shift) @ W1) * dis   [128 -> 32] ----
__global__ __launch_bounds__(256) void k_conv1t(const float* __restrict__ x,
                                                const int* __restrict__ batch,
                                                const float* __restrict__ scale,
                                                const float* __restrict__ shift,
                                                const float* __restrict__ W1,
                                                const float* __restrict__ dis,
                                                float* __restrict__ p1) {
    __shared__ float sW[FIN * 32];     // 16 KB
    __shared__ float sx[128 * FIN];    // 64 KB
    int t = threadIdx.x;
    const float4* W4 = (const float4*)W1;
    for (int i = t; i < FIN * 32 / 4; i += 256) ((float4*)sW)[i] = W4[i];
    int base = blockIdx.x * 128;
    const float4* x4 = (const float4*)x;
    const float4* sc4 = (const float4*)scale;
    const float4* sh4 = (const float4*)shift;
    for (int i = t; i < 128 * 32; i += 256) {
        int nl = i >> 5, c4 = i & 31;
        int n = base + nl;
        float4 r = {0.f, 0.f, 0.f, 0.f};
        if (n < NN) {
            int g = batch[n];
            float4 xv = x4[n * 32 + c4];
            float4 sc = sc4[g * 32 + c4];
            float4 sh = sh4[g * 32 + c4];
            r.x = xv.x * sc.x + sh.x;
            r.y = xv.y * sc.y + sh.y;
            r.z = xv.z * sc.z + sh.z;
            r.w = xv.w * sc.w + sh.w;
        }
        ((float4*)sx)[i] = r;
    }
    __syncthreads();
    int kq = t & 7;          // float4 group of output channels (k0 = kq*4)
    int n0 = (t >> 3) * 4;   // 4 consecutive nodes
    float4 acc[4];
#pragma unroll
    for (int i = 0; i < 4; ++i) acc[i] = {0.f, 0.f, 0.f, 0.f};
    const float4* sx4 = (const float4*)sx;
    const float4* sW4 = (const float4*)sW;
    for (int c4 = 0; c4 < 32; ++c4) {
        float4 w0 = sW4[(c4 * 4 + 0) * 8 + kq];
        float4 w1 = sW4[(c4 * 4 + 1) * 8 + kq];
        float4 w2 = sW4[(c4 * 4 + 2) * 8 + kq];
        float4 w3 = sW4[(c4 * 4 + 3) * 8 + kq];
#pragma unroll
        for (int i = 0; i < 4; ++i) {
            float4 a = sx4[(n0 + i) * 32 + c4];
            acc[i].x += a.x * w0.x + a.y * w1.x + a.z * w2.x + a.w * w3.x;
            acc[i].y += a.x * w0.y + a.y * w1.y + a.z * w2.y + a.w * w3.y;
            acc[i].z += a.x * w0.z + a.y * w1.z + a.z * w2.z + a.w * w3.z;
            acc[i].w += a.x * w0.w + a.y * w1.w + a.z * w2.w + a.w * w3.w;
        }
    }
#pragma unroll
    for (int i = 0; i < 4; ++i) {
        int n = base + n0 + i;
        if (n < NN) {
            float d = dis[n];
            float4 r;
            r.x = acc[i].x * d; r.y = acc[i].y * d;
            r.z = acc[i].z * d; r.w = acc[i].w * d;
            ((float4*)p1)[n * 8 + kq] = r;
        }
    }
}

// ---- gather1 (C=32, float4) + conv1 epilogue: p2 = relu(dis*(self+neigh)+b1)*dis ----
__global__ __launch_bounds__(256) void k_gather1(const float* __restrict__ p1,
                                                 const int* __restrict__ rowstart,
                                                 const int* __restrict__ csr,
                                                 const float* __restrict__ dis,
                                                 const float* __restrict__ b1,
                                                 float* __restrict__ p2) {
    int tid = blockIdx.x * 256 + threadIdx.x;  // NN*8 threads
    int n = tid >> 3, c4 = tid & 7;
    const float4* p1_4 = (const float4*)p1;
    int s = rowstart[n], e = rowstart[n + 1];
    float4 agg = p1_4[n * 8 + c4];  // self-loop (p = h*dis already)
    int j = s;
    for (; j + 1 < e; j += 2) {
        float4 v0 = p1_4[csr[j] * 8 + c4];
        float4 v1 = p1_4[csr[j + 1] * 8 + c4];
        agg.x += v0.x + v1.x; agg.y += v0.y + v1.y;
        agg.z += v0.z + v1.z; agg.w += v0.w + v1.w;
    }
    if (j < e) {
        float4 v = p1_4[csr[j] * 8 + c4];
        agg.x += v.x; agg.y += v.y; agg.z += v.z; agg.w += v.w;
    }
    float d = dis[n];
    float4 bb = ((const float4*)b1)[c4];
    float4 r;
    r.x = fmaxf(d * agg.x + bb.x, 0.f) * d;
    r.y = fmaxf(d * agg.y + bb.y, 0.f) * d;
    r.z = fmaxf(d * agg.z + bb.z, 0.f) * d;
    r.w = fmaxf(d * agg.w + bb.w, 0.f) * d;
    ((float4*)p2)[n * 8 + c4] = r;
}

// ---- fused gather2 + conv2: p3 = relu((dis*(self+neigh))@W2 + b2)*dis  [32->64], 16 nodes/block ----
__global__ __launch_bounds__(256) void k_conv2g(const float* __restrict__ p2,
                                                const int* __restrict__ rowstart,
                                                const int* __restrict__ csr,
                                                const float* __restrict__ dis,
                                                const float* __restrict__ W2,
                                                const float* __restrict__ b2v,
                                                float* __restrict__ p3) {
    __shared__ float sW[32 * 64];        // 8 KB
    __shared__ float4 spart[16 * 16];    // 16 nodes x 2 halves x 8 c4 = 4 KB
    __shared__ float sa[16 * 32];        // 2 KB
    int t = threadIdx.x;
    const float4* W4 = (const float4*)W2;
    for (int i = t; i < 32 * 64 / 4; i += 256) ((float4*)sW)[i] = W4[i];
    int base = blockIdx.x * 16;
    const float4* p2_4 = (const float4*)p2;
    {
        int node = t >> 4, c4 = t & 7, half = (t >> 3) & 1;
        int n = base + node;
        int s = rowstart[n], e = rowstart[n + 1];
        float4 agg = {0.f, 0.f, 0.f, 0.f};
        if (half == 0) {
            agg = p2_4[n * 8 + c4];  // self
            for (int j = s; j < e; j += 2) {
                float4 v = p2_4[csr[j] * 8 + c4];
                agg.x += v.x; agg.y += v.y; agg.z += v.z; agg.w += v.w;
            }
        } else {
            for (int j = s + 1; j < e; j += 2) {
                float4 v = p2_4[csr[j] * 8 + c4];
                agg.x += v.x; agg.y += v.y; agg.z += v.z; agg.w += v.w;
            }
        }
        spart[node * 16 + half * 8 + c4] = agg;
    }
    __syncthreads();
    if (t < 128) {
        int nd = t >> 3, cc = t & 7;
        float4 a = spart[nd * 16 + cc], b = spart[nd * 16 + 8 + cc];
        float d = dis[base + nd];
        float4 r;
        r.x = d * (a.x + b.x); r.y = d * (a.y + b.y);
        r.z = d * (a.z + b.z); r.w = d * (a.w + b.w);
        ((float4*)sa)[nd * 8 + cc] = r;
    }
    __syncthreads();
    int k = t & 63, grp = t >> 6;
    float acc[4] = {0.f, 0.f, 0.f, 0.f};
    for (int c = 0; c < 32; ++c) {
        float w = sW[c * 64 + k];
#pragma unroll
        for (int q = 0; q < 4; ++q) acc[q] += sa[(grp * 4 + q) * 32 + c] * w;
    }
    float bb = b2v[k];
#pragma unroll
    for (int q = 0; q < 4; ++q) {
        int n = base + grp * 4 + q;
        float h = fmaxf(acc[q] + bb, 0.f);
        p3[n * 64 + k] = h * dis[n];
    }
}

// ---- gather3 (C=64, float4, 16 lanes/node): a3 = dis*(self+neigh) ----
__global__ __launch_bounds__(256) void k_gather3(const float* __restrict__ p3,
                                                 const int* __restrict__ rowstart,
                                                 const int* __restrict__ csr,
                                                 const float* __restrict__ dis,
                                                 float* __restrict__ a3) {
    int tid = blockIdx.x * 256 + threadIdx.x;  // NN*16 threads
    int n = tid >> 4, c4 = tid & 15;
    const float4* p3_4 = (const float4*)p3;
    int s = rowstart[n], e = rowstart[n + 1];
    float4 agg = p3_4[n * 16 + c4];  // self
    int j = s;
    for (; j + 1 < e; j += 2) {
        float4 v0 = p3_4[csr[j] * 16 + c4];
        float4 v1 = p3_4[csr[j + 1] * 16 + c4];
        agg.x += v0.x + v1.x; agg.y += v0.y + v1.y;
        agg.z += v0.z + v1.z; agg.w += v0.w + v1.w;
    }
    if (j < e) {
        float4 v = p3_4[csr[j] * 16 + c4];
        agg.x += v.x; agg.y += v.y; agg.z += v.z; agg.w += v.w;
    }
    float d = dis[n];
    float4 r;
    r.x = d * agg.x; r.y = d * agg.y; r.z = d * agg.z; r.w = d * agg.w;
    ((float4*)a3)[n * 16 + c4] = r;
}

// ---- conv3 + run-length max-pool: 64 nodes/block, 8-node x 4-channel register tiles ----
__global__ __launch_bounds__(256) void k_conv3t(const float* __restrict__ a3,
                                                const float* __restrict__ W3,
                                                const float* __restrict__ b3v,
                                                const int* __restrict__ batch,
                                                unsigned int* __restrict__ pooled) {
    __shared__ float sW[64 * 128];   // 32 KB
    __shared__ float sa[64 * 64];    // 16 KB
    __shared__ int sbatch[64];
    int t = threadIdx.x;
    const float4* W4 = (const float4*)W3;
    for (int i = t; i < 64 * 128 / 4; i += 256) ((float4*)sW)[i] = W4[i];
    int base = blockIdx.x * 64;
    if (t < 64) sbatch[t] = batch[base + t];
    const float4* a3_4 = (const float4*)a3;
    for (int i = t; i < 64 * 16; i += 256) ((float4*)sa)[i] = a3_4[(size_t)base * 16 + i];
    __syncthreads();
    int k0 = (t & 31) * 4;   // 4 consecutive output channels
    int n0 = (t >> 5) * 8;   // 8 consecutive nodes
    float acc[8][4];
#pragma unroll
    for (int i = 0; i < 8; ++i)
#pragma unroll
        for (int j = 0; j < 4; ++j) acc[i][j] = 0.f;
    const float4* sa4 = (const float4*)sa;
    for (int c4 = 0; c4 < 16; ++c4) {
        float4 w0 = *(const float4*)&sW[(c4 * 4 + 0) * 128 + k0];
        float4 w1 = *(const float4*)&sW[(c4 * 4 + 1) * 128 + k0];
        float4 w2 = *(const float4*)&sW[(c4 * 4 + 2) * 128 + k0];
        float4 w3 = *(const float4*)&sW[(c4 * 4 + 3) * 128 + k0];
#pragma unroll
        for (int i = 0; i < 8; ++i) {
            float4 a = sa4[(n0 + i) * 16 + c4];
            acc[i][0] += a.x * w0.x + a.y * w1.x + a.z * w2.x + a.w * w3.x;
            acc[i][1] += a.x * w0.y + a.y * w1.y + a.z * w2.y + a.w * w3.y;
            acc[i][2] += a.x * w0.z + a.y * w1.z + a.z * w2.z + a.w * w3.z;
            acc[i][3] += a.x * w0.w + a.y * w1.w + a.z * w2.w + a.w * w3.w;
        }
    }
    float4 bb = *(const float4*)&b3v[k0];
    float bbv[4] = {bb.x, bb.y, bb.z, bb.w};
    // run-length pool over this thread's 8 contiguous nodes, 4 channels
    int curg = sbatch[n0];
    float cm[4] = {0.f, 0.f, 0.f, 0.f};
#pragma unroll
    for (int i = 0; i < 8; ++i) {
        int g = sbatch[n0 + i];
        if (g != curg) {
#pragma unroll
            for (int j = 0; j < 4; ++j) {
                atomicMax(&pooled[curg * 128 + k0 + j], __float_as_uint(cm[j]));
                cm[j] = 0.f;
            }
            curg = g;
        }
#pragma unroll
        for (int j = 0; j < 4; ++j)
            cm[j] = fmaxf(cm[j], fmaxf(acc[i][j] + bbv[j], 0.f));
    }
#pragma unroll
    for (int j = 0; j < 4; ++j)
        atomicMax(&pooled[curg * 128 + k0 + j], __float_as_uint(cm[j]));
}

// ---- lin1: mid = relu(pooled @ lin1_W + b), 8 graphs/block ----
__global__ __launch_bounds__(256) void k_lin1(const float* __restrict__ pooled,
                                              const float* __restrict__ W,
                                              const float* __restrict__ bias,
                                              float* __restrict__ mid) {
    __shared__ float sp[8 * 128];  // 4 KB
    int t = threadIdx.x;
    int base = blockIdx.x * 8;
    for (int i = t; i < 8 * 128; i += 256) sp[i] = pooled[base * 128 + i];
    __syncthreads();
    float acc[8] = {0.f, 0.f, 0.f, 0.f, 0.f, 0.f, 0.f, 0.f};
    for (int c = 0; c < 128; ++c) {
        float w = W[c * 256 + t];
#pragma unroll
        for (int gl = 0; gl < 8; ++gl) acc[gl] += sp[gl * 128 + c] * w;
    }
    float bb = bias[t];
#pragma unroll
    for (int gl = 0; gl < 8; ++gl) mid[(base + gl) * 256 + t] = fmaxf(acc[gl] + bb, 0.f);
}

// ---- lin2: out = mid @ lin2_W + b, 16 graphs/block ----
__global__ __launch_bounds__(128) void k_lin2(const float* __restrict__ mid,
                                              const float* __restrict__ W,
                                              const float* __restrict__ bias,
                                              float* __restrict__ out) {
    __shared__ float sm[16 * 256];  // 16 KB
    int t = threadIdx.x;
    int base = blockIdx.x * 16;
    for (int i = t; i < 16 * 256; i += 128) sm[i] = mid[base * 256 + i];
    __syncthreads();
    float acc[16];
#pragma unroll
    for (int i = 0; i < 16; ++i) acc[i] = 0.f;
    for (int c = 0; c < 256; ++c) {
        float w = W[c * 128 + t];
#pragma unroll
        for (int gl = 0; gl < 16; ++gl) acc[gl] += sm[gl * 256 + c] * w;
    }
    float bb = bias[t];
#pragma unroll
    for (int gl = 0; gl < 16; ++gl)
        out[(base + gl) * 128 + t] = acc[gl] + bb;
}

extern "C" void kernel_launch(void* const* d_in, const int* in_sizes, int n_in,
                              void* d_out, int out_size, void* d_ws, size_t ws_size,
                              hipStream_t stream) {
    (void)in_sizes; (void)n_in; (void)out_size; (void)ws_size;
    const float* x   = (const float*)d_in[0];
    const int* ei    = (const int*)d_in[1];
    const int* src = ei;
    const int* dst = ei + NE;
    const int* batch = (const int*)d_in[2];
    const float* nw  = (const float*)d_in[3];
    const float* nb  = (const float*)d_in[4];
    const float* W1  = (const float*)d_in[5];
    const float* b1  = (const float*)d_in[6];
    const float* W2  = (const float*)d_in[7];
    const float* b2  = (const float*)d_in[8];
    const float* W3  = (const float*)d_in[9];
    const float* b3  = (const float*)d_in[10];
    const float* l1W = (const float*)d_in[11];
    const float* l1b = (const float*)d_in[12];
    const float* l2W = (const float*)d_in[13];
    const float* l2b = (const float*)d_in[14];
    float* out = (float*)d_out;

    char* wsp = (char*)d_ws;
    int*   cnt      = (int*)wsp;   wsp += (size_t)NN * 4;        // becomes dis in place
    int*   rowstart = (int*)wsp;   wsp += (size_t)(NN + 1) * 4;
    int*   cursor   = (int*)wsp;   wsp += (size_t)NN * 4;
    int*   bsum     = (int*)wsp;   wsp += (size_t)NBS * 4;
    int*   bpre     = (int*)wsp;   wsp += (size_t)NBS * 4;
    int*   startg   = (int*)wsp;   wsp += (size_t)(NG + 1) * 4;
    int*   csr      = (int*)wsp;   wsp += (size_t)NE * 4;        // 3.2 MB
    wsp += ((256 - ((uintptr_t)wsp & 255)) & 255);
    float* scale   = (float*)wsp; wsp += (size_t)NG * 128 * 4;   // 4 MB
    float* shift   = (float*)wsp; wsp += (size_t)NG * 128 * 4;   // 4 MB
    float* pooled  = (float*)wsp; wsp += (size_t)NG * 128 * 4;   // 4 MB
    float* regionA = (float*)wsp; wsp += (size_t)NN * 64 * 4;    // p1|p2, later a3
    float* regionB = (float*)wsp; wsp += (size_t)NN * 64 * 4;    // p3, later mid

    float* dis  = (float*)cnt;  // in-place after k_dis
    float* p1   = regionA;
    float* p2   = regionA + (size_t)NN * 32;
    float* p3   = regionB;
    float* a3   = regionA;      // p1/p2 dead after k_conv2g
    float* mid  = regionB;      // p3 dead after k_gather3

    // CSR prep
    hipMemsetAsync(cnt, 0, (size_t)NN * 4, stream);
    k_cnt<<<(NE + 255) / 256, 256, 0, stream>>>(dst, cnt);
    k_blocksum<<<NBS, 256, 0, stream>>>(cnt, bsum);
    k_scanb<<<1, 1024, 0, stream>>>(bsum, bpre);
    k_scanchunk<<<NBS, 256, 0, stream>>>(cnt, bpre, rowstart);
    k_dis<<<(NN + 255) / 256, 256, 0, stream>>>(cnt);  // cnt -> dis in place
    hipMemcpyAsync(cursor, rowstart, (size_t)NN * 4, hipMemcpyDeviceToDevice, stream);
    k_fill<<<(NE + 255) / 256, 256, 0, stream>>>(src, dst, cursor, csr);

    // layer 1: stats (per-graph) then register-tiled conv1 (contiguous nodes)
    k_starts<<<(NN + 255) / 256, 256, 0, stream>>>(batch, startg);
    k_stats2<<<NG, 256, 0, stream>>>(x, startg, nw, nb, scale, shift);
    k_conv1t<<<(NN + 127) / 128, 256, 0, stream>>>(x, batch, scale, shift, W1, dis, p1);
    k_gather1<<<NN * 8 / 256, 256, 0, stream>>>(p1, rowstart, csr, dis, b1, p2);
    // layer 2 (fused gather+matmul)
    k_conv2g<<<NN / 16, 256, 0, stream>>>(p2, rowstart, csr, dis, W2, b2, p3);
    // layer 3 (separate gather, then register-tiled matmul + run-length pool)
    k_gather3<<<NN * 16 / 256, 256, 0, stream>>>(p3, rowstart, csr, dis, a3);
    hipMemsetAsync(pooled, 0, (size_t)NG * 128 * 4, stream);
    k_conv3t<<<NN / 64, 256, 0, stream>>>(a3, W3, b3, batch, (unsigned int*)pooled);

    // head
    k_lin1<<<NG / 8, 256, 0, stream>>>(pooled, l1W, l1b, mid);
    k_lin2<<<NG / 16, 128, 0, stream>>>(mid, l2W, l2b, out);
}

// Round 9
// 567.274 us; speedup vs baseline: 1.2775x; 1.0113x over previous
//
#include <hip/hip_runtime.h>
#include <stdint.h>

#define NN 200000
#define NE 800000
#define FIN 128
#define NG 8000
#define EPSV 1e-5f
#define NBS ((NN + 255) / 256)   // 782 scan blocks

// ---- int degree histogram over dst ----
__global__ void k_cnt(const int* __restrict__ dst, int* __restrict__ cnt) {
    int e = blockIdx.x * 256 + threadIdx.x;
    if (e < NE) atomicAdd(&cnt[dst[e]], 1);
}

// ---- per-256-chunk sums ----
__global__ void k_blocksum(const int* __restrict__ cnt, int* __restrict__ bsum) {
    __shared__ int sh[256];
    int b = blockIdx.x, t = threadIdx.x;
    int idx = b * 256 + t;
    sh[t] = (idx < NN) ? cnt[idx] : 0;
    __syncthreads();
    for (int o = 128; o > 0; o >>= 1) {
        if (t < o) sh[t] += sh[t + o];
        __syncthreads();
    }
    if (t == 0) bsum[b] = sh[0];
}

// ---- single-block scan of chunk sums -> exclusive prefixes ----
__global__ __launch_bounds__(1024) void k_scanb(const int* __restrict__ bsum, int* __restrict__ bpre) {
    __shared__ int sh[1024];
    int t = threadIdx.x;
    int v = (t < NBS) ? bsum[t] : 0;
    sh[t] = v;
    __syncthreads();
    for (int o = 1; o < 1024; o <<= 1) {
        int add = (t >= o) ? sh[t - o] : 0;
        __syncthreads();
        sh[t] += add;
        __syncthreads();
    }
    if (t < NBS) bpre[t] = sh[t] - v;  // exclusive
}

// ---- per-chunk scan + offset -> rowstart (exclusive) ----
__global__ void k_scanchunk(const int* __restrict__ cnt, const int* __restrict__ bpre,
                            int* __restrict__ rowstart) {
    __shared__ int sh[256];
    int b = blockIdx.x, t = threadIdx.x;
    int idx = b * 256 + t;
    int v = (idx < NN) ? cnt[idx] : 0;
    sh[t] = v;
    __syncthreads();
    for (int o = 1; o < 256; o <<= 1) {
        int add = (t >= o) ? sh[t - o] : 0;
        __syncthreads();
        sh[t] += add;
        __syncthreads();
    }
    if (idx < NN) rowstart[idx] = bpre[b] + sh[t] - v;
    if (idx == 0) rowstart[NN] = NE;
}

// ---- dis = rsqrt(1+deg), IN PLACE over cnt (int -> float reinterpret) ----
__global__ void k_dis(int* __restrict__ cnt) {
    int n = blockIdx.x * 256 + threadIdx.x;
    if (n < NN) {
        float d = rsqrtf(1.0f + (float)cnt[n]);
        ((float*)cnt)[n] = d;
    }
}

// ---- fill CSR: csr[pos] = src, bucketed by dst ----
__global__ void k_fill(const int* __restrict__ src, const int* __restrict__ dst,
                       int* __restrict__ cursor, int* __restrict__ csr) {
    int e = blockIdx.x * 256 + threadIdx.x;
    if (e < NE) {
        int pos = atomicAdd(&cursor[dst[e]], 1);
        csr[pos] = src[e];
    }
}

// ---- graph start offsets from sorted batch ----
__global__ void k_starts(const int* __restrict__ batch, int* __restrict__ startg) {
    int n = blockIdx.x * 256 + threadIdx.x;
    if (n >= NN) return;
    int b = batch[n];
    int prev = (n == 0) ? -1 : batch[n - 1];
    for (int g = prev + 1; g <= b; ++g) startg[g] = n;
    if (n == NN - 1) {
        for (int g = b + 1; g <= NG; ++g) startg[g] = NN;
    }
}

// ---- per-graph instance-norm stats, latency-tolerant: 8 node slots x 32 float4 lanes ----
__global__ __launch_bounds__(256) void k_stats2(const float* __restrict__ x,
                                                const int* __restrict__ startg,
                                                const float* __restrict__ nw,
                                                const float* __restrict__ nb,
                                                float* __restrict__ scale,
                                                float* __restrict__ shift) {
    __shared__ float4 rsum[256], rsq[256];
    int g = blockIdx.x;
    int s = startg[g], e = startg[g + 1];
    if (s == e) return;
    int t = threadIdx.x;
    int slot = t >> 5, c4 = t & 31;
    const float4* x4 = (const float4*)x;
    float4 sum = {0.f, 0.f, 0.f, 0.f}, sq = {0.f, 0.f, 0.f, 0.f};
    for (int n = s + slot; n < e; n += 8) {
        float4 v = x4[n * 32 + c4];
        sum.x += v.x; sum.y += v.y; sum.z += v.z; sum.w += v.w;
        sq.x += v.x * v.x; sq.y += v.y * v.y; sq.z += v.z * v.z; sq.w += v.w * v.w;
    }
    rsum[slot * 32 + c4] = sum;
    rsq[slot * 32 + c4] = sq;
    __syncthreads();
    if (t < 32) {
        float4 S = rsum[t], Q = rsq[t];
#pragma unroll
        for (int sl = 1; sl < 8; ++sl) {
            float4 a = rsum[sl * 32 + t], b = rsq[sl * 32 + t];
            S.x += a.x; S.y += a.y; S.z += a.z; S.w += a.w;
            Q.x += b.x; Q.y += b.y; Q.z += b.z; Q.w += b.w;
        }
        float inv = 1.0f / (float)(e - s);
        float w = nw[0], b = nb[0];
        float4 sc, sh;
        {
            float m = S.x * inv, v = fmaxf(Q.x * inv - m * m, 0.f);
            float is = rsqrtf(v + EPSV); sc.x = is * w; sh.x = b - m * is * w;
        }
        {
            float m = S.y * inv, v = fmaxf(Q.y * inv - m * m, 0.f);
            float is = rsqrtf(v + EPSV); sc.y = is * w; sh.y = b - m * is * w;
        }
        {
            float m = S.z * inv, v = fmaxf(Q.z * inv - m * m, 0.f);
            float is = rsqrtf(v + EPSV); sc.z = is * w; sh.z = b - m * is * w;
        }
        {
            float m = S.w * inv, v = fmaxf(Q.w * inv - m * m, 0.f);
            float is = rsqrtf(v + EPSV); sc.w = is * w; sh.w = b - m * is * w;
        }
        ((float4*)scale)[g * 32 + t] = sc;
        ((float4*)shift)[g * 32 + t] = sh;
    }
}

// swizzled sx index (float4 units): rotates bank group by node-group, conflict-free
#define SXIDX(n, c4) ((n) * 32 + (((c4) + ((n) >> 2)) & 31))

// ---- conv1, register-tiled: 128 contiguous nodes/block, 4-node x 4-ch tiles
//      p1 = ((x*scale+shift) @ W1) * dis   [128 -> 32] ----
__global__ __launch_bounds__(256) void k_conv1t(const float* __restrict__ x,
                                                const int* __restrict__ batch,
                                                const float* __restrict__ scale,
                                                const float* __restrict__ shift,
                                                const float* __restrict__ W1,
                                                const float* __restrict__ dis,
                                                float* __restrict__ p1) {
    __shared__ float sW[FIN * 32];     // 16 KB
    __shared__ float sx[128 * FIN];    // 64 KB (swizzled float4 layout)
    int t = threadIdx.x;
    const float4* W4 = (const float4*)W1;
    for (int i = t; i < FIN * 32 / 4; i += 256) ((float4*)sW)[i] = W4[i];
    int base = blockIdx.x * 128;
    const float4* x4 = (const float4*)x;
    const float4* sc4 = (const float4*)scale;
    const float4* sh4 = (const float4*)shift;
    for (int i = t; i < 128 * 32; i += 256) {
        int nl = i >> 5, c4 = i & 31;
        int n = base + nl;
        float4 r = {0.f, 0.f, 0.f, 0.f};
        if (n < NN) {
            int g = batch[n];
            float4 xv = x4[n * 32 + c4];
            float4 sc = sc4[g * 32 + c4];
            float4 sh = sh4[g * 32 + c4];
            r.x = xv.x * sc.x + sh.x;
            r.y = xv.y * sc.y + sh.y;
            r.z = xv.z * sc.z + sh.z;
            r.w = xv.w * sc.w + sh.w;
        }
        ((float4*)sx)[SXIDX(nl, c4)] = r;
    }
    __syncthreads();
    int kq = t & 7;          // float4 group of output channels (k0 = kq*4)
    int n0 = (t >> 3) * 4;   // 4 consecutive nodes
    float4 acc[4];
#pragma unroll
    for (int i = 0; i < 4; ++i) acc[i] = {0.f, 0.f, 0.f, 0.f};
    const float4* sx4 = (const float4*)sx;
    const float4* sW4 = (const float4*)sW;
    for (int c4 = 0; c4 < 32; ++c4) {
        float4 w0 = sW4[(c4 * 4 + 0) * 8 + kq];
        float4 w1 = sW4[(c4 * 4 + 1) * 8 + kq];
        float4 w2 = sW4[(c4 * 4 + 2) * 8 + kq];
        float4 w3 = sW4[(c4 * 4 + 3) * 8 + kq];
#pragma unroll
        for (int i = 0; i < 4; ++i) {
            float4 a = sx4[SXIDX(n0 + i, c4)];
            acc[i].x += a.x * w0.x + a.y * w1.x + a.z * w2.x + a.w * w3.x;
            acc[i].y += a.x * w0.y + a.y * w1.y + a.z * w2.y + a.w * w3.y;
            acc[i].z += a.x * w0.z + a.y * w1.z + a.z * w2.z + a.w * w3.z;
            acc[i].w += a.x * w0.w + a.y * w1.w + a.z * w2.w + a.w * w3.w;
        }
    }
#pragma unroll
    for (int i = 0; i < 4; ++i) {
        int n = base + n0 + i;
        if (n < NN) {
            float d = dis[n];
            float4 r;
            r.x = acc[i].x * d; r.y = acc[i].y * d;
            r.z = acc[i].z * d; r.w = acc[i].w * d;
            ((float4*)p1)[n * 8 + kq] = r;
        }
    }
}

// ---- gather1 (C=32, float4) + conv1 epilogue: p2 = relu(dis*(self+neigh)+b1)*dis ----
__global__ __launch_bounds__(256) void k_gather1(const float* __restrict__ p1,
                                                 const int* __restrict__ rowstart,
                                                 const int* __restrict__ csr,
                                                 const float* __restrict__ dis,
                                                 const float* __restrict__ b1,
                                                 float* __restrict__ p2) {
    int tid = blockIdx.x * 256 + threadIdx.x;  // NN*8 threads
    int n = tid >> 3, c4 = tid & 7;
    const float4* p1_4 = (const float4*)p1;
    int s = rowstart[n], e = rowstart[n + 1];
    float4 agg = p1_4[n * 8 + c4];  // self-loop (p = h*dis already)
    int j = s;
    for (; j + 1 < e; j += 2) {
        float4 v0 = p1_4[csr[j] * 8 + c4];
        float4 v1 = p1_4[csr[j + 1] * 8 + c4];
        agg.x += v0.x + v1.x; agg.y += v0.y + v1.y;
        agg.z += v0.z + v1.z; agg.w += v0.w + v1.w;
    }
    if (j < e) {
        float4 v = p1_4[csr[j] * 8 + c4];
        agg.x += v.x; agg.y += v.y; agg.z += v.z; agg.w += v.w;
    }
    float d = dis[n];
    float4 bb = ((const float4*)b1)[c4];
    float4 r;
    r.x = fmaxf(d * agg.x + bb.x, 0.f) * d;
    r.y = fmaxf(d * agg.y + bb.y, 0.f) * d;
    r.z = fmaxf(d * agg.z + bb.z, 0.f) * d;
    r.w = fmaxf(d * agg.w + bb.w, 0.f) * d;
    ((float4*)p2)[n * 8 + c4] = r;
}

// ---- fused gather2 + conv2: p3 = relu((dis*(self+neigh))@W2 + b2)*dis  [32->64], 16 nodes/block ----
__global__ __launch_bounds__(256) void k_conv2g(const float* __restrict__ p2,
                                                const int* __restrict__ rowstart,
                                                const int* __restrict__ csr,
                                                const float* __restrict__ dis,
                                                const float* __restrict__ W2,
                                                const float* __restrict__ b2v,
                                                float* __restrict__ p3) {
    __shared__ float sW[32 * 64];        // 8 KB
    __shared__ float4 spart[16 * 16];    // 16 nodes x 2 halves x 8 c4 = 4 KB
    __shared__ float sa[16 * 32];        // 2 KB
    int t = threadIdx.x;
    const float4* W4 = (const float4*)W2;
    for (int i = t; i < 32 * 64 / 4; i += 256) ((float4*)sW)[i] = W4[i];
    int base = blockIdx.x * 16;
    const float4* p2_4 = (const float4*)p2;
    {
        int node = t >> 4, c4 = t & 7, half = (t >> 3) & 1;
        int n = base + node;
        int s = rowstart[n], e = rowstart[n + 1];
        float4 agg = {0.f, 0.f, 0.f, 0.f};
        if (half == 0) {
            agg = p2_4[n * 8 + c4];  // self
            for (int j = s; j < e; j += 2) {
                float4 v = p2_4[csr[j] * 8 + c4];
                agg.x += v.x; agg.y += v.y; agg.z += v.z; agg.w += v.w;
            }
        } else {
            for (int j = s + 1; j < e; j += 2) {
                float4 v = p2_4[csr[j] * 8 + c4];
                agg.x += v.x; agg.y += v.y; agg.z += v.z; agg.w += v.w;
            }
        }
        spart[node * 16 + half * 8 + c4] = agg;
    }
    __syncthreads();
    if (t < 128) {
        int nd = t >> 3, cc = t & 7;
        float4 a = spart[nd * 16 + cc], b = spart[nd * 16 + 8 + cc];
        float d = dis[base + nd];
        float4 r;
        r.x = d * (a.x + b.x); r.y = d * (a.y + b.y);
        r.z = d * (a.z + b.z); r.w = d * (a.w + b.w);
        ((float4*)sa)[nd * 8 + cc] = r;
    }
    __syncthreads();
    int k = t & 63, grp = t >> 6;
    float acc[4] = {0.f, 0.f, 0.f, 0.f};
    for (int c = 0; c < 32; ++c) {
        float w = sW[c * 64 + k];
#pragma unroll
        for (int q = 0; q < 4; ++q) acc[q] += sa[(grp * 4 + q) * 32 + c] * w;
    }
    float bb = b2v[k];
#pragma unroll
    for (int q = 0; q < 4; ++q) {
        int n = base + grp * 4 + q;
        float h = fmaxf(acc[q] + bb, 0.f);
        p3[n * 64 + k] = h * dis[n];
    }
}

// ---- gather3 (C=64, float4, 16 lanes/node): a3 = dis*(self+neigh) ----
__global__ __launch_bounds__(256) void k_gather3(const float* __restrict__ p3,
                                                 const int* __restrict__ rowstart,
                                                 const int* __restrict__ csr,
                                                 const float* __restrict__ dis,
                                                 float* __restrict__ a3) {
    int tid = blockIdx.x * 256 + threadIdx.x;  // NN*16 threads
    int n = tid >> 4, c4 = tid & 15;
    const float4* p3_4 = (const float4*)p3;
    int s = rowstart[n], e = rowstart[n + 1];
    float4 agg = p3_4[n * 16 + c4];  // self
    int j = s;
    for (; j + 1 < e; j += 2) {
        float4 v0 = p3_4[csr[j] * 16 + c4];
        float4 v1 = p3_4[csr[j + 1] * 16 + c4];
        agg.x += v0.x + v1.x; agg.y += v0.y + v1.y;
        agg.z += v0.z + v1.z; agg.w += v0.w + v1.w;
    }
    if (j < e) {
        float4 v = p3_4[csr[j] * 16 + c4];
        agg.x += v.x; agg.y += v.y; agg.z += v.z; agg.w += v.w;
    }
    float d = dis[n];
    float4 r;
    r.x = d * agg.x; r.y = d * agg.y; r.z = d * agg.z; r.w = d * agg.w;
    ((float4*)a3)[n * 16 + c4] = r;
}

// ---- conv3 + run-length max-pool: 64 nodes/block, 8-node x 4-channel register tiles ----
__global__ __launch_bounds__(256) void k_conv3t(const float* __restrict__ a3,
                                                const float* __restrict__ W3,
                                                const float* __restrict__ b3v,
                                                const int* __restrict__ batch,
                                                unsigned int* __restrict__ pooled) {
    __shared__ float sW[64 * 128];   // 32 KB
    __shared__ float sa[64 * 64];    // 16 KB
    __shared__ int sbatch[64];
    int t = threadIdx.x;
    const float4* W4 = (const float4*)W3;
    for (int i = t; i < 64 * 128 / 4; i += 256) ((float4*)sW)[i] = W4[i];
    int base = blockIdx.x * 64;
    if (t < 64) sbatch[t] = batch[base + t];
    const float4* a3_4 = (const float4*)a3;
    for (int i = t; i < 64 * 16; i += 256) ((float4*)sa)[i] = a3_4[(size_t)base * 16 + i];
    __syncthreads();
    int k0 = (t & 31) * 4;   // 4 consecutive output channels
    int n0 = (t >> 5) * 8;   // 8 consecutive nodes
    float acc[8][4];
#pragma unroll
    for (int i = 0; i < 8; ++i)
#pragma unroll
        for (int j = 0; j < 4; ++j) acc[i][j] = 0.f;
    const float4* sa4 = (const float4*)sa;
    for (int c4 = 0; c4 < 16; ++c4) {
        float4 w0 = *(const float4*)&sW[(c4 * 4 + 0) * 128 + k0];
        float4 w1 = *(const float4*)&sW[(c4 * 4 + 1) * 128 + k0];
        float4 w2 = *(const float4*)&sW[(c4 * 4 + 2) * 128 + k0];
        float4 w3 = *(const float4*)&sW[(c4 * 4 + 3) * 128 + k0];
#pragma unroll
        for (int i = 0; i < 8; ++i) {
            float4 a = sa4[(n0 + i) * 16 + c4];
            acc[i][0] += a.x * w0.x + a.y * w1.x + a.z * w2.x + a.w * w3.x;
            acc[i][1] += a.x * w0.y + a.y * w1.y + a.z * w2.y + a.w * w3.y;
            acc[i][2] += a.x * w0.z + a.y * w1.z + a.z * w2.z + a.w * w3.z;
            acc[i][3] += a.x * w0.w + a.y * w1.w + a.z * w2.w + a.w * w3.w;
        }
    }
    float4 bb = *(const float4*)&b3v[k0];
    float bbv[4] = {bb.x, bb.y, bb.z, bb.w};
    // run-length pool over this thread's 8 contiguous nodes, 4 channels
    int curg = sbatch[n0];
    float cm[4] = {0.f, 0.f, 0.f, 0.f};
#pragma unroll
    for (int i = 0; i < 8; ++i) {
        int g = sbatch[n0 + i];
        if (g != curg) {
#pragma unroll
            for (int j = 0; j < 4; ++j) {
                atomicMax(&pooled[curg * 128 + k0 + j], __float_as_uint(cm[j]));
                cm[j] = 0.f;
            }
            curg = g;
        }
#pragma unroll
        for (int j = 0; j < 4; ++j)
            cm[j] = fmaxf(cm[j], fmaxf(acc[i][j] + bbv[j], 0.f));
    }
#pragma unroll
    for (int j = 0; j < 4; ++j)
        atomicMax(&pooled[curg * 128 + k0 + j], __float_as_uint(cm[j]));
}

// ---- lin1: mid = relu(pooled @ lin1_W + b), 8 graphs/block ----
__global__ __launch_bounds__(256) void k_lin1(const float* __restrict__ pooled,
                                              const float* __restrict__ W,
                                              const float* __restrict__ bias,
                                              float* __restrict__ mid) {
    __shared__ float sp[8 * 128];  // 4 KB
    int t = threadIdx.x;
    int base = blockIdx.x * 8;
    for (int i = t; i < 8 * 128; i += 256) sp[i] = pooled[base * 128 + i];
    __syncthreads();
    float acc[8] = {0.f, 0.f, 0.f, 0.f, 0.f, 0.f, 0.f, 0.f};
    for (int c = 0; c < 128; ++c) {
        float w = W[c * 256 + t];
#pragma unroll
        for (int gl = 0; gl < 8; ++gl) acc[gl] += sp[gl * 128 + c] * w;
    }
    float bb = bias[t];
#pragma unroll
    for (int gl = 0; gl < 8; ++gl) mid[(base + gl) * 256 + t] = fmaxf(acc[gl] + bb, 0.f);
}

// ---- lin2: out = mid @ lin2_W + b, 16 graphs/block ----
__global__ __launch_bounds__(128) void k_lin2(const float* __restrict__ mid,
                                              const float* __restrict__ W,
                                              const float* __restrict__ bias,
                                              float* __restrict__ out) {
    __shared__ float sm[16 * 256];  // 16 KB
    int t = threadIdx.x;
    int base = blockIdx.x * 16;
    for (int i = t; i < 16 * 256; i += 128) sm[i] = mid[base * 256 + i];
    __syncthreads();
    float acc[16];
#pragma unroll
    for (int i = 0; i < 16; ++i) acc[i] = 0.f;
    for (int c = 0; c < 256; ++c) {
        float w = W[c * 128 + t];
#pragma unroll
        for (int gl = 0; gl < 16; ++gl) acc[gl] += sm[gl * 256 + c] * w;
    }
    float bb = bias[t];
#pragma unroll
    for (int gl = 0; gl < 16; ++gl)
        out[(base + gl) * 128 + t] = acc[gl] + bb;
}

extern "C" void kernel_launch(void* const* d_in, const int* in_sizes, int n_in,
                              void* d_out, int out_size, void* d_ws, size_t ws_size,
                              hipStream_t stream) {
    (void)in_sizes; (void)n_in; (void)out_size; (void)ws_size;
    const float* x   = (const float*)d_in[0];
    const int* ei    = (const int*)d_in[1];
    const int* src = ei;
    const int* dst = ei + NE;
    const int* batch = (const int*)d_in[2];
    const float* nw  = (const float*)d_in[3];
    const float* nb  = (const float*)d_in[4];
    const float* W1  = (const float*)d_in[5];
    const float* b1  = (const float*)d_in[6];
    const float* W2  = (const float*)d_in[7];
    const float* b2  = (const float*)d_in[8];
    const float* W3  = (const float*)d_in[9];
    const float* b3  = (const float*)d_in[10];
    const float* l1W = (const float*)d_in[11];
    const float* l1b = (const float*)d_in[12];
    const float* l2W = (const float*)d_in[13];
    const float* l2b = (const float*)d_in[14];
    float* out = (float*)d_out;

    char* wsp = (char*)d_ws;
    int*   cnt      = (int*)wsp;   wsp += (size_t)NN * 4;        // becomes dis in place
    int*   rowstart = (int*)wsp;   wsp += (size_t)(NN + 1) * 4;
    int*   cursor   = (int*)wsp;   wsp += (size_t)NN * 4;
    int*   bsum     = (int*)wsp;   wsp += (size_t)NBS * 4;
    int*   bpre     = (int*)wsp;   wsp += (size_t)NBS * 4;
    int*   startg   = (int*)wsp;   wsp += (size_t)(NG + 1) * 4;
    int*   csr      = (int*)wsp;   wsp += (size_t)NE * 4;        // 3.2 MB
    wsp += ((256 - ((uintptr_t)wsp & 255)) & 255);
    float* scale   = (float*)wsp; wsp += (size_t)NG * 128 * 4;   // 4 MB
    float* shift   = (float*)wsp; wsp += (size_t)NG * 128 * 4;   // 4 MB
    float* pooled  = (float*)wsp; wsp += (size_t)NG * 128 * 4;   // 4 MB
    float* regionA = (float*)wsp; wsp += (size_t)NN * 64 * 4;    // p1|p2, later a3
    float* regionB = (float*)wsp; wsp += (size_t)NN * 64 * 4;    // p3, later mid

    float* dis  = (float*)cnt;  // in-place after k_dis
    float* p1   = regionA;
    float* p2   = regionA + (size_t)NN * 32;
    float* p3   = regionB;
    float* a3   = regionA;      // p1/p2 dead after k_conv2g
    float* mid  = regionB;      // p3 dead after k_gather3

    // CSR prep
    hipMemsetAsync(cnt, 0, (size_t)NN * 4, stream);
    k_cnt<<<(NE + 255) / 256, 256, 0, stream>>>(dst, cnt);
    k_blocksum<<<NBS, 256, 0, stream>>>(cnt, bsum);
    k_scanb<<<1, 1024, 0, stream>>>(bsum, bpre);
    k_scanchunk<<<NBS, 256, 0, stream>>>(cnt, bpre, rowstart);
    k_dis<<<(NN + 255) / 256, 256, 0, stream>>>(cnt);  // cnt -> dis in place
    hipMemcpyAsync(cursor, rowstart, (size_t)NN * 4, hipMemcpyDeviceToDevice, stream);
    k_fill<<<(NE + 255) / 256, 256, 0, stream>>>(src, dst, cursor, csr);

    // layer 1: stats (per-graph) then register-tiled conv1 (contiguous nodes)
    k_starts<<<(NN + 255) / 256, 256, 0, stream>>>(batch, startg);
    k_stats2<<<NG, 256, 0, stream>>>(x, startg, nw, nb, scale, shift);
    k_conv1t<<<(NN + 127) / 128, 256, 0, stream>>>(x, batch, scale, shift, W1, dis, p1);
    k_gather1<<<NN * 8 / 256, 256, 0, stream>>>(p1, rowstart, csr, dis, b1, p2);
    // layer 2 (fused gather+matmul)
    k_conv2g<<<NN / 16, 256, 0, stream>>>(p2, rowstart, csr, dis, W2, b2, p3);
    // layer 3 (separate gather, then register-tiled matmul + run-length pool)
    k_gather3<<<NN * 16 / 256, 256, 0, stream>>>(p3, rowstart, csr, dis, a3);
    hipMemsetAsync(pooled, 0, (size_t)NG * 128 * 4, stream);
    k_conv3t<<<NN / 64, 256, 0, stream>>>(a3, W3, b3, batch, (unsigned int*)pooled);

    // head
    k_lin1<<<NG / 8, 256, 0, stream>>>(pooled, l1W, l1b, mid);
    k_lin2<<<NG / 16, 128, 0, stream>>>(mid, l2W, l2b, out);
}

// Round 10
// 545.580 us; speedup vs baseline: 1.3283x; 1.0398x over previous
//
#include <hip/hip_runtime.h>
#include <hip/hip_bf16.h>
#include <stdint.h>

#define NN 200000
#define NE 800000
#define FIN 128
#define NG 8000
#define EPSV 1e-5f
#define NBS ((NN + 255) / 256)   // 782 scan blocks

// bf16 helpers: load-convert (exact) and pack with RNE
static __device__ __forceinline__ void u2f(uint4 v, float4& lo, float4& hi) {
    lo.x = __uint_as_float(v.x << 16); lo.y = __uint_as_float(v.x & 0xffff0000u);
    lo.z = __uint_as_float(v.y << 16); lo.w = __uint_as_float(v.y & 0xffff0000u);
    hi.x = __uint_as_float(v.z << 16); hi.y = __uint_as_float(v.z & 0xffff0000u);
    hi.z = __uint_as_float(v.w << 16); hi.w = __uint_as_float(v.w & 0xffff0000u);
}
static __device__ __forceinline__ unsigned int pk(float a, float b) {
    __hip_bfloat16 x = __float2bfloat16(a), y = __float2bfloat16(b);
    return (unsigned int)(*(unsigned short*)&x) | ((unsigned int)(*(unsigned short*)&y) << 16);
}

// ---- int degree histogram over dst ----
__global__ void k_cnt(const int* __restrict__ dst, int* __restrict__ cnt) {
    int e = blockIdx.x * 256 + threadIdx.x;
    if (e < NE) atomicAdd(&cnt[dst[e]], 1);
}

// ---- per-256-chunk sums ----
__global__ void k_blocksum(const int* __restrict__ cnt, int* __restrict__ bsum) {
    __shared__ int sh[256];
    int b = blockIdx.x, t = threadIdx.x;
    int idx = b * 256 + t;
    sh[t] = (idx < NN) ? cnt[idx] : 0;
    __syncthreads();
    for (int o = 128; o > 0; o >>= 1) {
        if (t < o) sh[t] += sh[t + o];
        __syncthreads();
    }
    if (t == 0) bsum[b] = sh[0];
}

// ---- single-block scan of chunk sums -> exclusive prefixes ----
__global__ __launch_bounds__(1024) void k_scanb(const int* __restrict__ bsum, int* __restrict__ bpre) {
    __shared__ int sh[1024];
    int t = threadIdx.x;
    int v = (t < NBS) ? bsum[t] : 0;
    sh[t] = v;
    __syncthreads();
    for (int o = 1; o < 1024; o <<= 1) {
        int add = (t >= o) ? sh[t - o] : 0;
        __syncthreads();
        sh[t] += add;
        __syncthreads();
    }
    if (t < NBS) bpre[t] = sh[t] - v;  // exclusive
}

// ---- per-chunk scan + offset -> rowstart (exclusive) ----
__global__ void k_scanchunk(const int* __restrict__ cnt, const int* __restrict__ bpre,
                            int* __restrict__ rowstart) {
    __shared__ int sh[256];
    int b = blockIdx.x, t = threadIdx.x;
    int idx = b * 256 + t;
    int v = (idx < NN) ? cnt[idx] : 0;
    sh[t] = v;
    __syncthreads();
    for (int o = 1; o < 256; o <<= 1) {
        int add = (t >= o) ? sh[t - o] : 0;
        __syncthreads();
        sh[t] += add;
        __syncthreads();
    }
    if (idx < NN) rowstart[idx] = bpre[b] + sh[t] - v;
    if (idx == 0) rowstart[NN] = NE;
}

// ---- dis = rsqrt(1+deg), IN PLACE over cnt (int -> float reinterpret) ----
__global__ void k_dis(int* __restrict__ cnt) {
    int n = blockIdx.x * 256 + threadIdx.x;
    if (n < NN) {
        float d = rsqrtf(1.0f + (float)cnt[n]);
        ((float*)cnt)[n] = d;
    }
}

// ---- fill CSR: csr[pos] = src, bucketed by dst ----
__global__ void k_fill(const int* __restrict__ src, const int* __restrict__ dst,
                       int* __restrict__ cursor, int* __restrict__ csr) {
    int e = blockIdx.x * 256 + threadIdx.x;
    if (e < NE) {
        int pos = atomicAdd(&cursor[dst[e]], 1);
        csr[pos] = src[e];
    }
}

// ---- graph start offsets from sorted batch ----
__global__ void k_starts(const int* __restrict__ batch, int* __restrict__ startg) {
    int n = blockIdx.x * 256 + threadIdx.x;
    if (n >= NN) return;
    int b = batch[n];
    int prev = (n == 0) ? -1 : batch[n - 1];
    for (int g = prev + 1; g <= b; ++g) startg[g] = n;
    if (n == NN - 1) {
        for (int g = b + 1; g <= NG; ++g) startg[g] = NN;
    }
}

// ---- per-graph instance-norm stats, latency-tolerant: 8 node slots x 32 float4 lanes ----
__global__ __launch_bounds__(256) void k_stats2(const float* __restrict__ x,
                                                const int* __restrict__ startg,
                                                const float* __restrict__ nw,
                                                const float* __restrict__ nb,
                                                float* __restrict__ scale,
                                                float* __restrict__ shift) {
    __shared__ float4 rsum[256], rsq[256];
    int g = blockIdx.x;
    int s = startg[g], e = startg[g + 1];
    if (s == e) return;
    int t = threadIdx.x;
    int slot = t >> 5, c4 = t & 31;
    const float4* x4 = (const float4*)x;
    float4 sum = {0.f, 0.f, 0.f, 0.f}, sq = {0.f, 0.f, 0.f, 0.f};
    for (int n = s + slot; n < e; n += 8) {
        float4 v = x4[n * 32 + c4];
        sum.x += v.x; sum.y += v.y; sum.z += v.z; sum.w += v.w;
        sq.x += v.x * v.x; sq.y += v.y * v.y; sq.z += v.z * v.z; sq.w += v.w * v.w;
    }
    rsum[slot * 32 + c4] = sum;
    rsq[slot * 32 + c4] = sq;
    __syncthreads();
    if (t < 32) {
        float4 S = rsum[t], Q = rsq[t];
#pragma unroll
        for (int sl = 1; sl < 8; ++sl) {
            float4 a = rsum[sl * 32 + t], b = rsq[sl * 32 + t];
            S.x += a.x; S.y += a.y; S.z += a.z; S.w += a.w;
            Q.x += b.x; Q.y += b.y; Q.z += b.z; Q.w += b.w;
        }
        float inv = 1.0f / (float)(e - s);
        float w = nw[0], b = nb[0];
        float4 sc, sh;
        {
            float m = S.x * inv, v = fmaxf(Q.x * inv - m * m, 0.f);
            float is = rsqrtf(v + EPSV); sc.x = is * w; sh.x = b - m * is * w;
        }
        {
            float m = S.y * inv, v = fmaxf(Q.y * inv - m * m, 0.f);
            float is = rsqrtf(v + EPSV); sc.y = is * w; sh.y = b - m * is * w;
        }
        {
            float m = S.z * inv, v = fmaxf(Q.z * inv - m * m, 0.f);
            float is = rsqrtf(v + EPSV); sc.z = is * w; sh.z = b - m * is * w;
        }
        {
            float m = S.w * inv, v = fmaxf(Q.w * inv - m * m, 0.f);
            float is = rsqrtf(v + EPSV); sc.w = is * w; sh.w = b - m * is * w;
        }
        ((float4*)scale)[g * 32 + t] = sc;
        ((float4*)shift)[g * 32 + t] = sh;
    }
}

// swizzled sx index (float4 units): rotate bank group by node-pair, conflict-free
#define SXIDX(n, c4) ((n) * 32 + (((c4) + ((n) >> 1)) & 31))

// ---- conv1, register-tiled: 64 contiguous nodes/block (48 KB LDS -> 3 blocks/CU),
//      2-node x 4-ch tiles;  p1 = ((x*scale+shift) @ W1) * dis   [128 -> 32] ----
__global__ __launch_bounds__(256) void k_conv1t(const float* __restrict__ x,
                                                const int* __restrict__ batch,
                                                const float* __restrict__ scale,
                                                const float* __restrict__ shift,
                                                const float* __restrict__ W1,
                                                const float* __restrict__ dis,
                                                float* __restrict__ p1) {
    __shared__ float sW[FIN * 32];    // 16 KB
    __shared__ float sx[64 * FIN];    // 32 KB (swizzled float4 layout)
    int t = threadIdx.x;
    const float4* W4 = (const float4*)W1;
    for (int i = t; i < FIN * 32 / 4; i += 256) ((float4*)sW)[i] = W4[i];
    int base = blockIdx.x * 64;       // NN % 64 == 0
    const float4* x4 = (const float4*)x;
    const float4* sc4 = (const float4*)scale;
    const float4* sh4 = (const float4*)shift;
    for (int i = t; i < 64 * 32; i += 256) {
        int nl = i >> 5, c4 = i & 31;
        int n = base + nl;
        int g = batch[n];
        float4 xv = x4[n * 32 + c4];
        float4 sc = sc4[g * 32 + c4];
        float4 sh = sh4[g * 32 + c4];
        float4 r;
        r.x = xv.x * sc.x + sh.x;
        r.y = xv.y * sc.y + sh.y;
        r.z = xv.z * sc.z + sh.z;
        r.w = xv.w * sc.w + sh.w;
        ((float4*)sx)[SXIDX(nl, c4)] = r;
    }
    __syncthreads();
    int kq = t & 7;          // float4 group of output channels
    int n0 = (t >> 3) * 2;   // 2 consecutive nodes
    float4 acc[2];
    acc[0] = {0.f, 0.f, 0.f, 0.f};
    acc[1] = {0.f, 0.f, 0.f, 0.f};
    const float4* sx4 = (const float4*)sx;
    const float4* sW4 = (const float4*)sW;
    for (int c4 = 0; c4 < 32; ++c4) {
        float4 w0 = sW4[(c4 * 4 + 0) * 8 + kq];
        float4 w1 = sW4[(c4 * 4 + 1) * 8 + kq];
        float4 w2 = sW4[(c4 * 4 + 2) * 8 + kq];
        float4 w3 = sW4[(c4 * 4 + 3) * 8 + kq];
#pragma unroll
        for (int i = 0; i < 2; ++i) {
            float4 a = sx4[SXIDX(n0 + i, c4)];
            acc[i].x += a.x * w0.x + a.y * w1.x + a.z * w2.x + a.w * w3.x;
            acc[i].y += a.x * w0.y + a.y * w1.y + a.z * w2.y + a.w * w3.y;
            acc[i].z += a.x * w0.z + a.y * w1.z + a.z * w2.z + a.w * w3.z;
            acc[i].w += a.x * w0.w + a.y * w1.w + a.z * w2.w + a.w * w3.w;
        }
    }
#pragma unroll
    for (int i = 0; i < 2; ++i) {
        int n = base + n0 + i;
        float d = dis[n];
        float4 r;
        r.x = acc[i].x * d; r.y = acc[i].y * d;
        r.z = acc[i].z * d; r.w = acc[i].w * d;
        ((float4*)p1)[n * 8 + kq] = r;
    }
}

// ---- gather1 (C=32, float4) + conv1 epilogue: p2 = relu(dis*(self+neigh)+b1)*dis ----
__global__ __launch_bounds__(256) void k_gather1(const float* __restrict__ p1,
                                                 const int* __restrict__ rowstart,
                                                 const int* __restrict__ csr,
                                                 const float* __restrict__ dis,
                                                 const float* __restrict__ b1,
                                                 float* __restrict__ p2) {
    int tid = blockIdx.x * 256 + threadIdx.x;  // NN*8 threads
    int n = tid >> 3, c4 = tid & 7;
    const float4* p1_4 = (const float4*)p1;
    int s = rowstart[n], e = rowstart[n + 1];
    float4 agg = p1_4[n * 8 + c4];  // self-loop (p = h*dis already)
    int j = s;
    for (; j + 1 < e; j += 2) {
        float4 v0 = p1_4[csr[j] * 8 + c4];
        float4 v1 = p1_4[csr[j + 1] * 8 + c4];
        agg.x += v0.x + v1.x; agg.y += v0.y + v1.y;
        agg.z += v0.z + v1.z; agg.w += v0.w + v1.w;
    }
    if (j < e) {
        float4 v = p1_4[csr[j] * 8 + c4];
        agg.x += v.x; agg.y += v.y; agg.z += v.z; agg.w += v.w;
    }
    float d = dis[n];
    float4 bb = ((const float4*)b1)[c4];
    float4 r;
    r.x = fmaxf(d * agg.x + bb.x, 0.f) * d;
    r.y = fmaxf(d * agg.y + bb.y, 0.f) * d;
    r.z = fmaxf(d * agg.z + bb.z, 0.f) * d;
    r.w = fmaxf(d * agg.w + bb.w, 0.f) * d;
    ((float4*)p2)[n * 8 + c4] = r;
}

// ---- fused gather2 + conv2: p3(bf16) = relu((dis*(self+neigh))@W2 + b2)*dis  [32->64] ----
__global__ __launch_bounds__(256) void k_conv2g(const float* __restrict__ p2,
                                                const int* __restrict__ rowstart,
                                                const int* __restrict__ csr,
                                                const float* __restrict__ dis,
                                                const float* __restrict__ W2,
                                                const float* __restrict__ b2v,
                                                __hip_bfloat16* __restrict__ p3h) {
    __shared__ float sW[32 * 64];        // 8 KB
    __shared__ float4 spart[16 * 16];    // 4 KB
    __shared__ float sa[16 * 32];        // 2 KB
    int t = threadIdx.x;
    const float4* W4 = (const float4*)W2;
    for (int i = t; i < 32 * 64 / 4; i += 256) ((float4*)sW)[i] = W4[i];
    int base = blockIdx.x * 16;
    const float4* p2_4 = (const float4*)p2;
    {
        int node = t >> 4, c4 = t & 7, half = (t >> 3) & 1;
        int n = base + node;
        int s = rowstart[n], e = rowstart[n + 1];
        float4 agg = {0.f, 0.f, 0.f, 0.f};
        if (half == 0) {
            agg = p2_4[n * 8 + c4];  // self
            for (int j = s; j < e; j += 2) {
                float4 v = p2_4[csr[j] * 8 + c4];
                agg.x += v.x; agg.y += v.y; agg.z += v.z; agg.w += v.w;
            }
        } else {
            for (int j = s + 1; j < e; j += 2) {
                float4 v = p2_4[csr[j] * 8 + c4];
                agg.x += v.x; agg.y += v.y; agg.z += v.z; agg.w += v.w;
            }
        }
        spart[node * 16 + half * 8 + c4] = agg;
    }
    __syncthreads();
    if (t < 128) {
        int nd = t >> 3, cc = t & 7;
        float4 a = spart[nd * 16 + cc], b = spart[nd * 16 + 8 + cc];
        float d = dis[base + nd];
        float4 r;
        r.x = d * (a.x + b.x); r.y = d * (a.y + b.y);
        r.z = d * (a.z + b.z); r.w = d * (a.w + b.w);
        ((float4*)sa)[nd * 8 + cc] = r;
    }
    __syncthreads();
    int k = t & 63, grp = t >> 6;
    float acc[4] = {0.f, 0.f, 0.f, 0.f};
    for (int c = 0; c < 32; ++c) {
        float w = sW[c * 64 + k];
#pragma unroll
        for (int q = 0; q < 4; ++q) acc[q] += sa[(grp * 4 + q) * 32 + c] * w;
    }
    float bb = b2v[k];
#pragma unroll
    for (int q = 0; q < 4; ++q) {
        int n = base + grp * 4 + q;
        float h = fmaxf(acc[q] + bb, 0.f);
        p3h[n * 64 + k] = __float2bfloat16(h * dis[n]);
    }
}

// ---- gather3 (C=64 bf16, 8 lanes/node, uint4 = 8 bf16): a3(bf16) = dis*(self+neigh) ----
__global__ __launch_bounds__(256) void k_gather3(const __hip_bfloat16* __restrict__ p3h,
                                                 const int* __restrict__ rowstart,
                                                 const int* __restrict__ csr,
                                                 const float* __restrict__ dis,
                                                 __hip_bfloat16* __restrict__ a3h) {
    int tid = blockIdx.x * 256 + threadIdx.x;  // NN*8 threads
    int n = tid >> 3, c8 = tid & 7;
    const uint4* p3q = (const uint4*)p3h;
    int s = rowstart[n], e = rowstart[n + 1];
    float4 alo, ahi;
    u2f(p3q[n * 8 + c8], alo, ahi);  // self
    int j = s;
    for (; j + 1 < e; j += 2) {
        float4 l0, h0, l1, h1;
        u2f(p3q[csr[j] * 8 + c8], l0, h0);
        u2f(p3q[csr[j + 1] * 8 + c8], l1, h1);
        alo.x += l0.x + l1.x; alo.y += l0.y + l1.y;
        alo.z += l0.z + l1.z; alo.w += l0.w + l1.w;
        ahi.x += h0.x + h1.x; ahi.y += h0.y + h1.y;
        ahi.z += h0.z + h1.z; ahi.w += h0.w + h1.w;
    }
    if (j < e) {
        float4 l0, h0;
        u2f(p3q[csr[j] * 8 + c8], l0, h0);
        alo.x += l0.x; alo.y += l0.y; alo.z += l0.z; alo.w += l0.w;
        ahi.x += h0.x; ahi.y += h0.y; ahi.z += h0.z; ahi.w += h0.w;
    }
    float d = dis[n];
    uint4 o;
    o.x = pk(d * alo.x, d * alo.y);
    o.y = pk(d * alo.z, d * alo.w);
    o.z = pk(d * ahi.x, d * ahi.y);
    o.w = pk(d * ahi.z, d * ahi.w);
    ((uint4*)a3h)[n * 8 + c8] = o;
}

// ---- conv3 + run-length max-pool: 64 nodes/block, 8-node x 4-channel register tiles ----
__global__ __launch_bounds__(256) void k_conv3t(const __hip_bfloat16* __restrict__ a3h,
                                                const float* __restrict__ W3,
                                                const float* __restrict__ b3v,
                                                const int* __restrict__ batch,
                                                unsigned int* __restrict__ pooled) {
    __shared__ float sW[64 * 128];   // 32 KB
    __shared__ float sa[64 * 64];    // 16 KB
    __shared__ int sbatch[64];
    int t = threadIdx.x;
    const float4* W4 = (const float4*)W3;
    for (int i = t; i < 64 * 128 / 4; i += 256) ((float4*)sW)[i] = W4[i];
    int base = blockIdx.x * 64;
    if (t < 64) sbatch[t] = batch[base + t];
    const uint4* a3q = (const uint4*)a3h;
    for (int i = t; i < 64 * 8; i += 256) {
        int nl = i >> 3, c8 = i & 7;
        float4 lo, hi;
        u2f(a3q[(size_t)base * 8 + i], lo, hi);
        ((float4*)sa)[nl * 16 + c8 * 2] = lo;
        ((float4*)sa)[nl * 16 + c8 * 2 + 1] = hi;
    }
    __syncthreads();
    int k0 = (t & 31) * 4;   // 4 consecutive output channels
    int n0 = (t >> 5) * 8;   // 8 consecutive nodes
    float acc[8][4];
#pragma unroll
    for (int i = 0; i < 8; ++i)
#pragma unroll
        for (int j = 0; j < 4; ++j) acc[i][j] = 0.f;
    const float4* sa4 = (const float4*)sa;
    for (int c4 = 0; c4 < 16; ++c4) {
        float4 w0 = *(const float4*)&sW[(c4 * 4 + 0) * 128 + k0];
        float4 w1 = *(const float4*)&sW[(c4 * 4 + 1) * 128 + k0];
        float4 w2 = *(const float4*)&sW[(c4 * 4 + 2) * 128 + k0];
        float4 w3 = *(const float4*)&sW[(c4 * 4 + 3) * 128 + k0];
#pragma unroll
        for (int i = 0; i < 8; ++i) {
            float4 a = sa4[(n0 + i) * 16 + c4];
            acc[i][0] += a.x * w0.x + a.y * w1.x + a.z * w2.x + a.w * w3.x;
            acc[i][1] += a.x * w0.y + a.y * w1.y + a.z * w2.y + a.w * w3.y;
            acc[i][2] += a.x * w0.z + a.y * w1.z + a.z * w2.z + a.w * w3.z;
            acc[i][3] += a.x * w0.w + a.y * w1.w + a.z * w2.w + a.w * w3.w;
        }
    }
    float4 bb = *(const float4*)&b3v[k0];
    float bbv[4] = {bb.x, bb.y, bb.z, bb.w};
    // run-length pool over this thread's 8 contiguous nodes, 4 channels
    int curg = sbatch[n0];
    float cm[4] = {0.f, 0.f, 0.f, 0.f};
#pragma unroll
    for (int i = 0; i < 8; ++i) {
        int g = sbatch[n0 + i];
        if (g != curg) {
#pragma unroll
            for (int j = 0; j < 4; ++j) {
                atomicMax(&pooled[curg * 128 + k0 + j], __float_as_uint(cm[j]));
                cm[j] = 0.f;
            }
            curg = g;
        }
#pragma unroll
        for (int j = 0; j < 4; ++j)
            cm[j] = fmaxf(cm[j], fmaxf(acc[i][j] + bbv[j], 0.f));
    }
#pragma unroll
    for (int j = 0; j < 4; ++j)
        atomicMax(&pooled[curg * 128 + k0 + j], __float_as_uint(cm[j]));
}

// ---- lin1: mid = relu(pooled @ lin1_W + b), 8 graphs/block ----
__global__ __launch_bounds__(256) void k_lin1(const float* __restrict__ pooled,
                                              const float* __restrict__ W,
                                              const float* __restrict__ bias,
                                              float* __restrict__ mid) {
    __shared__ float sp[8 * 128];  // 4 KB
    int t = threadIdx.x;
    int base = blockIdx.x * 8;
    for (int i = t; i < 8 * 128; i += 256) sp[i] = pooled[base * 128 + i];
    __syncthreads();
    float acc[8] = {0.f, 0.f, 0.f, 0.f, 0.f, 0.f, 0.f, 0.f};
    for (int c = 0; c < 128; ++c) {
        float w = W[c * 256 + t];
#pragma unroll
        for (int gl = 0; gl < 8; ++gl) acc[gl] += sp[gl * 128 + c] * w;
    }
    float bb = bias[t];
#pragma unroll
    for (int gl = 0; gl < 8; ++gl) mid[(base + gl) * 256 + t] = fmaxf(acc[gl] + bb, 0.f);
}

// ---- lin2: out = mid @ lin2_W + b, 16 graphs/block ----
__global__ __launch_bounds__(128) void k_lin2(const float* __restrict__ mid,
                                              const float* __restrict__ W,
                                              const float* __restrict__ bias,
                                              float* __restrict__ out) {
    __shared__ float sm[16 * 256];  // 16 KB
    int t = threadIdx.x;
    int base = blockIdx.x * 16;
    for (int i = t; i < 16 * 256; i += 128) sm[i] = mid[base * 256 + i];
    __syncthreads();
    float acc[16];
#pragma unroll
    for (int i = 0; i < 16; ++i) acc[i] = 0.f;
    for (int c = 0; c < 256; ++c) {
        float w = W[c * 128 + t];
#pragma unroll
        for (int gl = 0; gl < 16; ++gl) acc[gl] += sm[gl * 256 + c] * w;
    }
    float bb = bias[t];
#pragma unroll
    for (int gl = 0; gl < 16; ++gl)
        out[(base + gl) * 128 + t] = acc[gl] + bb;
}

extern "C" void kernel_launch(void* const* d_in, const int* in_sizes, int n_in,
                              void* d_out, int out_size, void* d_ws, size_t ws_size,
                              hipStream_t stream) {
    (void)in_sizes; (void)n_in; (void)out_size; (void)ws_size;
    const float* x   = (const float*)d_in[0];
    const int* ei    = (const int*)d_in[1];
    const int* src = ei;
    const int* dst = ei + NE;
    const int* batch = (const int*)d_in[2];
    const float* nw  = (const float*)d_in[3];
    const float* nb  = (const float*)d_in[4];
    const float* W1  = (const float*)d_in[5];
    const float* b1  = (const float*)d_in[6];
    const float* W2  = (const float*)d_in[7];
    const float* b2  = (const float*)d_in[8];
    const float* W3  = (const float*)d_in[9];
    const float* b3  = (const float*)d_in[10];
    const float* l1W = (const float*)d_in[11];
    const float* l1b = (const float*)d_in[12];
    const float* l2W = (const float*)d_in[13];
    const float* l2b = (const float*)d_in[14];
    float* out = (float*)d_out;

    char* wsp = (char*)d_ws;
    int*   cnt      = (int*)wsp;   wsp += (size_t)NN * 4;        // becomes dis in place
    int*   rowstart = (int*)wsp;   wsp += (size_t)(NN + 1) * 4;
    int*   cursor   = (int*)wsp;   wsp += (size_t)NN * 4;
    int*   bsum     = (int*)wsp;   wsp += (size_t)NBS * 4;
    int*   bpre     = (int*)wsp;   wsp += (size_t)NBS * 4;
    int*   startg   = (int*)wsp;   wsp += (size_t)(NG + 1) * 4;
    int*   csr      = (int*)wsp;   wsp += (size_t)NE * 4;        // 3.2 MB
    wsp += ((256 - ((uintptr_t)wsp & 255)) & 255);
    float* scale   = (float*)wsp; wsp += (size_t)NG * 128 * 4;   // 4 MB
    float* shift   = (float*)wsp; wsp += (size_t)NG * 128 * 4;   // 4 MB
    float* pooled  = (float*)wsp; wsp += (size_t)NG * 128 * 4;   // 4 MB
    float* regionA = (float*)wsp; wsp += (size_t)NN * 64 * 4;    // p1|p2, later a3h
    float* regionB = (float*)wsp; wsp += (size_t)NN * 64 * 4;    // p3h, later mid

    float* dis  = (float*)cnt;  // in-place after k_dis
    float* p1   = regionA;
    float* p2   = regionA + (size_t)NN * 32;
    __hip_bfloat16* p3h = (__hip_bfloat16*)regionB;  // NN*64*2 B = 25.6 MB
    __hip_bfloat16* a3h = (__hip_bfloat16*)regionA;  // p1/p2 dead after k_conv2g
    float* mid  = regionB;      // p3h dead after k_gather3

    // CSR prep
    hipMemsetAsync(cnt, 0, (size_t)NN * 4, stream);
    k_cnt<<<(NE + 255) / 256, 256, 0, stream>>>(dst, cnt);
    k_blocksum<<<NBS, 256, 0, stream>>>(cnt, bsum);
    k_scanb<<<1, 1024, 0, stream>>>(bsum, bpre);
    k_scanchunk<<<NBS, 256, 0, stream>>>(cnt, bpre, rowstart);
    k_dis<<<(NN + 255) / 256, 256, 0, stream>>>(cnt);  // cnt -> dis in place
    hipMemcpyAsync(cursor, rowstart, (size_t)NN * 4, hipMemcpyDeviceToDevice, stream);
    k_fill<<<(NE + 255) / 256, 256, 0, stream>>>(src, dst, cursor, csr);

    // layer 1: stats (per-graph) then register-tiled conv1 (64-node blocks)
    k_starts<<<(NN + 255) / 256, 256, 0, stream>>>(batch, startg);
    k_stats2<<<NG, 256, 0, stream>>>(x, startg, nw, nb, scale, shift);
    k_conv1t<<<NN / 64, 256, 0, stream>>>(x, batch, scale, shift, W1, dis, p1);
    k_gather1<<<NN * 8 / 256, 256, 0, stream>>>(p1, rowstart, csr, dis, b1, p2);
    // layer 2 (fused gather+matmul, bf16 p3 store)
    k_conv2g<<<NN / 16, 256, 0, stream>>>(p2, rowstart, csr, dis, W2, b2, p3h);
    // layer 3 (bf16 gather, then register-tiled matmul + run-length pool)
    k_gather3<<<NN * 8 / 256, 256, 0, stream>>>(p3h, rowstart, csr, dis, a3h);
    hipMemsetAsync(pooled, 0, (size_t)NG * 128 * 4, stream);
    k_conv3t<<<NN / 64, 256, 0, stream>>>(a3h, W3, b3, batch, (unsigned int*)pooled);

    // head
    k_lin1<<<NG / 8, 256, 0, stream>>>(pooled, l1W, l1b, mid);
    k_lin2<<<NG / 16, 128, 0, stream>>>(mid, l2W, l2b, out);
}